// Round 11
// baseline (458.647 us; speedup 1.0000x reference)
//
#include <hip/hip_runtime.h>
#include <math.h>

#define DDIM 64
#define BUCKET 1024             // nodes per binning bucket
#define LRSHIFT 17              // packed: col [0,17), lrow [17,27), val [32,64)
#define CMASK 0x1FFFF
#define LRMASK 0x3FF
#define NBLK 1024
#define TPB_BIN 512
#define TPB_CP 512
#define MAXNB 128               // max buckets (NB = ceil(100000/1024) = 98)

typedef unsigned long long ull;
typedef _Float16 half2_t __attribute__((ext_vector_type(2)));

__device__ inline unsigned int bf16_hi(float v) {       // RNE bf16 bits in high 16
    unsigned int a = __float_as_uint(v);
    return (a + 0x7fffu + ((a >> 16) & 1u)) & 0xffff0000u;
}

__device__ inline unsigned int pk_f16x2(float lo, float hi) {
    return __builtin_bit_cast(unsigned int, __builtin_amdgcn_cvt_pkrtz(lo, hi));
}

// ---- init global fill counters (cacheline-padded: stride 16 ints) ----
__global__ void init_fill_kernel(int* __restrict__ gfill_r, int* __restrict__ gfill_c,
                                 int NB, int cap) {
    int k = blockIdx.x * blockDim.x + threadIdx.x;
    if (k < NB) {
        gfill_r[k * 16] = k * cap;
        gfill_c[k * 16] = k * cap;
    }
}

// ---- fused binning: per-wave count, BLOCK-level reserve + place ----
__global__ __launch_bounds__(TPB_BIN)
void binning_kernel(const int* __restrict__ erow, const int* __restrict__ ecol,
                    const float* __restrict__ evals,
                    int* __restrict__ gfill_r, int* __restrict__ gfill_c,
                    ull* __restrict__ br, unsigned int* __restrict__ bc,
                    int E, int NB, int chunk) {
    __shared__ int hr[8][MAXNB];
    __shared__ int hc[8][MAXNB];
    __shared__ int fr[MAXNB];
    __shared__ int fc[MAXNB];
    int t = threadIdx.x;
    int wv = t >> 6;
    for (int k = t; k < 8 * MAXNB; k += TPB_BIN) { (&hr[0][0])[k] = 0; (&hc[0][0])[k] = 0; }
    __syncthreads();
    int lo = blockIdx.x * chunk;
    int hi = min(E, lo + chunk);
    for (int i = lo + t; i < hi; i += TPB_BIN) {
        atomicAdd(&hr[wv][erow[i] >> 10], 1);
        atomicAdd(&hc[wv][ecol[i] >> 10], 1);
    }
    __syncthreads();
    if (t < NB) {
        int sr = 0, sc = 0;
        #pragma unroll
        for (int w2 = 0; w2 < 8; w2++) { sr += hr[w2][t]; sc += hc[w2][t]; }
        fr[t] = atomicAdd(&gfill_r[t * 16], sr);
        fc[t] = atomicAdd(&gfill_c[t * 16], sc);
    }
    __syncthreads();
    for (int i = lo + t; i < hi; i += TPB_BIN) {
        int r = erow[i];
        int c = ecol[i];
        float v = evals[i];
        int pos = atomicAdd(&fr[r >> 10], 1);
        br[pos] = ((ull)__float_as_uint(v) << 32)
                | ((ull)(r & 1023) << LRSHIFT) | (unsigned)c;
        int pos2 = atomicAdd(&fc[c >> 10], 1);
        bc[pos2] = bf16_hi(v) | (unsigned)(c & 1023);   // 4 B packed
    }
}

// ---- count: block (bucket b, chunk ch) reads its 1/8 edge slice ONCE ----
__global__ __launch_bounds__(TPB_CP)
void count_kernel(const ull* __restrict__ br, const unsigned int* __restrict__ bc,
                  const int* __restrict__ gfill_r, const int* __restrict__ gfill_c,
                  int* __restrict__ subcnt, float* __restrict__ subds,
                  float* __restrict__ subdsc, int cap) {
    __shared__ int cnt[BUCKET];
    __shared__ float ds[BUCKET];
    __shared__ float dsc[BUCKET];
    int b = blockIdx.x >> 3, ch = blockIdx.x & 7;
    int t = threadIdx.x;
    for (int k = t; k < BUCKET; k += TPB_CP) { cnt[k] = 0; ds[k] = 0.0f; dsc[k] = 0.0f; }
    __syncthreads();
    int s = b * cap;
    int e = gfill_r[b * 16];
    int len = ((e - s) + 7) >> 3;
    int cs = s + ch * len, ce = min(e, cs + len);
    for (int i = cs + t; i < ce; i += TPB_CP) {
        ull p = br[i];
        int lr = (int)((p >> LRSHIFT) & LRMASK);
        atomicAdd(&cnt[lr], 1);
        atomicAdd(&ds[lr], __uint_as_float((unsigned)(p >> 32)));
    }
    int e2 = gfill_c[b * 16];
    int len2 = ((e2 - s) + 7) >> 3;
    int cs2 = s + ch * len2, ce2 = min(e2, cs2 + len2);
    for (int i = cs2 + t; i < ce2; i += TPB_CP) {
        unsigned int p = bc[i];
        atomicAdd(&dsc[p & 0x3FFu], __uint_as_float(p & 0xffff0000u));
    }
    __syncthreads();
    size_t base = ((size_t)b * 8 + ch) * BUCKET;
    for (int k = t; k < BUCKET; k += TPB_CP) {
        subcnt[base + k] = cnt[k];
        subds[base + k]  = ds[k];
        subdsc[base + k] = dsc[k];
    }
}

// ---- combine: per-bucket scan -> rowstart/rowend, per-chunk bases, inv_r, inv_c ----
__global__ __launch_bounds__(1024)
void combine_kernel(int* __restrict__ subcnt, const float* __restrict__ subds,
                    const float* __restrict__ subdsc,
                    int* __restrict__ rowstart, int* __restrict__ rowend,
                    float* __restrict__ inv_r, float* __restrict__ inv_c,
                    int N, int cap) {
    __shared__ int tot[BUCKET];
    int b = blockIdx.x, t = threadIdx.x;
    size_t base = (size_t)b * 8 * BUCKET;
    int c8[8];
    int sum = 0;
    #pragma unroll
    for (int c = 0; c < 8; c++) { c8[c] = subcnt[base + c * BUCKET + t]; sum += c8[c]; }
    tot[t] = sum;
    __syncthreads();
    for (int off = 1; off < BUCKET; off <<= 1) {
        int v = (t >= off) ? tot[t - off] : 0;
        __syncthreads();
        tot[t] += v;
        __syncthreads();
    }
    int excl = tot[t] - sum;
    int node = b * BUCKET + t;
    int s = b * cap;
    if (node < N) {
        rowstart[node] = s + excl;
        rowend[node]   = s + excl + sum;
    }
    int run = s + excl;
    #pragma unroll
    for (int c = 0; c < 8; c++) { int v = c8[c]; subcnt[base + c * BUCKET + t] = run; run += v; }
    float d = 0.0f, dc = 0.0f;
    #pragma unroll
    for (int c = 0; c < 8; c++) { d += subds[base + c * BUCKET + t]; dc += subdsc[base + c * BUCKET + t]; }
    inv_r[b * BUCKET + t] = 1.0f / (sqrtf(d) + 1e-8f);
    inv_c[b * BUCKET + t] = 1.0f / (sqrtf(dc) + 1e-8f);
}

// ---- place: ranked placement; weight folded & stored as DUPLICATED f16x2 ----
__global__ __launch_bounds__(TPB_CP)
void place_kernel(const ull* __restrict__ br, const int* __restrict__ gfill_r,
                  const int* __restrict__ pbase, const float* __restrict__ inv_r,
                  const float* __restrict__ inv_c,
                  int2* __restrict__ cw, int cap) {
    __shared__ int fill[BUCKET];
    __shared__ float irs[BUCKET];
    int b = blockIdx.x >> 3, ch = blockIdx.x & 7;
    int t = threadIdx.x;
    size_t pb = ((size_t)b * 8 + ch) * BUCKET;
    for (int k = t; k < BUCKET; k += TPB_CP) {
        fill[k] = pbase[pb + k];
        irs[k]  = inv_r[b * BUCKET + k];
    }
    __syncthreads();
    int s = b * cap;
    int e = gfill_r[b * 16];
    int len = ((e - s) + 7) >> 3;
    int cs = s + ch * len, ce = min(e, cs + len);
    for (int i = cs + t; i < ce; i += TPB_CP) {
        ull p = br[i];
        int c = (int)(p & CMASK);
        int lr = (int)((p >> LRSHIFT) & LRMASK);
        float v = __uint_as_float((unsigned)(p >> 32));
        int pos = atomicAdd(&fill[lr], 1);
        float wv = v * inv_c[c] * irs[lr];
        int2 pk;
        pk.x = c;
        pk.y = (int)pk_f16x2(wv, wv);      // duplicated f16 weight
        cw[pos] = pk;
    }
}

// ---- fused: acc = nf (fp32), fb0 = f16(nf) ----
__global__ void cvt_kernel(const float* __restrict__ src, float* __restrict__ acc,
                           unsigned int* __restrict__ dst, long n2) {
    long i = (long)blockIdx.x * blockDim.x + threadIdx.x;
    if (i < n2) {
        float2 v = ((const float2*)src)[i];
        ((float2*)acc)[i] = v;
        dst[i] = pk_f16x2(v.x, v.y);
    }
}

// ---- SpMM: wave per row, edge pairs, f16 gather + v_pk_fma_f16 (no perms) ----
__global__ __launch_bounds__(256)
void spmm_f16_kernel(const int* __restrict__ rowstart, const int* __restrict__ rowend,
                     const int2* __restrict__ cw,
                     const unsigned short* __restrict__ fin,
                     unsigned short* __restrict__ fout,
                     float* __restrict__ acc, int N) {
    int wid = blockIdx.x * (blockDim.x >> 6) + (threadIdx.x >> 6);   // row
    if (wid >= N) return;
    int lane = threadIdx.x & 63;
    int g = lane >> 3;          // edge-pair slot 0..7 (16 edges per iteration)
    int h = lane & 7;           // feature chunk (8 f16 = 16 B)
    int s = rowstart[wid], e = rowend[wid];
    half2_t a2[8];              // [0..3]: even-edge partials, [4..7]: odd-edge partials
    #pragma unroll
    for (int k = 0; k < 8; k++) a2[k] = (half2_t)0;

    int nfull = (e - s) >> 4;
    int base = s;
    for (int it = 0; it < nfull; it++, base += 16) {
        int j0 = base + 2 * g;
        int2 p0 = cw[j0];
        int2 p1 = cw[j0 + 1];
        uint4 q0 = ((const uint4*)(fin + ((long)p0.x << 6)))[h];
        uint4 q1 = ((const uint4*)(fin + ((long)p1.x << 6)))[h];
        half2_t w0 = __builtin_bit_cast(half2_t, (unsigned)p0.y);
        half2_t w1 = __builtin_bit_cast(half2_t, (unsigned)p1.y);
        a2[0] += w0 * __builtin_bit_cast(half2_t, q0.x);
        a2[1] += w0 * __builtin_bit_cast(half2_t, q0.y);
        a2[2] += w0 * __builtin_bit_cast(half2_t, q0.z);
        a2[3] += w0 * __builtin_bit_cast(half2_t, q0.w);
        a2[4] += w1 * __builtin_bit_cast(half2_t, q1.x);
        a2[5] += w1 * __builtin_bit_cast(half2_t, q1.y);
        a2[6] += w1 * __builtin_bit_cast(half2_t, q1.z);
        a2[7] += w1 * __builtin_bit_cast(half2_t, q1.w);
    }
    if (base < e) {
        // tail: mask weights by validity; clamp col for bucket-end poison.
        int j0 = base + 2 * g, j1 = j0 + 1;
        int2 p0 = cw[j0];
        int2 p1 = cw[j1];
        int c0 = p0.x & CMASK, c1 = p1.x & CMASK;
        half2_t w0 = (j0 < e) ? __builtin_bit_cast(half2_t, (unsigned)p0.y) : (half2_t)0;
        half2_t w1 = (j1 < e) ? __builtin_bit_cast(half2_t, (unsigned)p1.y) : (half2_t)0;
        uint4 q0 = ((const uint4*)(fin + ((long)c0 << 6)))[h];
        uint4 q1 = ((const uint4*)(fin + ((long)c1 << 6)))[h];
        a2[0] += w0 * __builtin_bit_cast(half2_t, q0.x);
        a2[1] += w0 * __builtin_bit_cast(half2_t, q0.y);
        a2[2] += w0 * __builtin_bit_cast(half2_t, q0.z);
        a2[3] += w0 * __builtin_bit_cast(half2_t, q0.w);
        a2[4] += w1 * __builtin_bit_cast(half2_t, q1.x);
        a2[5] += w1 * __builtin_bit_cast(half2_t, q1.y);
        a2[6] += w1 * __builtin_bit_cast(half2_t, q1.z);
        a2[7] += w1 * __builtin_bit_cast(half2_t, q1.w);
    }

    // combine parities in f32
    float a[8];
    #pragma unroll
    for (int k = 0; k < 4; k++) {
        a[2 * k]     = (float)a2[k][0] + (float)a2[k + 4][0];
        a[2 * k + 1] = (float)a2[k][1] + (float)a2[k + 4][1];
    }
    // reduce over the 8 pair slots (lane bits 3,4,5)
    #pragma unroll
    for (int k = 0; k < 8; k++) {
        a[k] += __shfl_xor(a[k], 8);
        a[k] += __shfl_xor(a[k], 16);
        a[k] += __shfl_xor(a[k], 32);
    }
    float ss = 0.0f;
    #pragma unroll
    for (int k = 0; k < 8; k++) ss += a[k] * a[k];
    ss += __shfl_xor(ss, 1);
    ss += __shfl_xor(ss, 2);
    ss += __shfl_xor(ss, 4);
    float s2 = 1.0f / fmaxf(sqrtf(ss), 1e-12f);
    if (g == 0) {
        uint4 o;
        o.x = pk_f16x2(a[0], a[1]);
        o.y = pk_f16x2(a[2], a[3]);
        o.z = pk_f16x2(a[4], a[5]);
        o.w = pk_f16x2(a[6], a[7]);
        ((uint4*)(fout + ((long)wid << 6)))[h] = o;
        float4* ap = (float4*)(acc + ((long)wid << 6)) + (h << 1);
        float4 c0 = ap[0], c1 = ap[1];
        c0.x += a[0] * s2; c0.y += a[1] * s2; c0.z += a[2] * s2; c0.w += a[3] * s2;
        c1.x += a[4] * s2; c1.y += a[5] * s2; c1.z += a[6] * s2; c1.w += a[7] * s2;
        ap[0] = c0;
        ap[1] = c1;
    }
}

// ---- BPR loss ----
__global__ void loss_terms_kernel(const float* __restrict__ acc,
                                  const int* __restrict__ a_id, const int* __restrict__ p_id,
                                  const int* __restrict__ n_id,
                                  float* __restrict__ terms, int B) {
    long gid = (long)blockIdx.x * blockDim.x + threadIdx.x;
    int b = (int)(gid >> 6);
    int lane = threadIdx.x & 63;
    if (b < B) {
        int ia = a_id[b], ip = p_id[b], in2 = n_id[b];
        float a = acc[(long)ia * DDIM + lane];
        float p = acc[(long)ip * DDIM + lane];
        float n = acc[(long)in2 * DDIM + lane];
        float dp = a * p, dn = a * n;
        #pragma unroll
        for (int off = 1; off < 64; off <<= 1) { dp += __shfl_xor(dp, off); dn += __shfl_xor(dn, off); }
        if (lane == 0) {
            float x = (dp - dn) * 0.0625f;   // node_rep = acc/4 -> preds scale 1/16
            terms[b] = fmaxf(-x, 0.0f) + log1pf(expf(-fabsf(x)));
        }
    }
}

__global__ void reduce_kernel(const float* __restrict__ terms, float* __restrict__ out, int B) {
    __shared__ float sm[256];
    float s = 0.0f;
    for (int i = threadIdx.x; i < B; i += 256) s += terms[i];
    sm[threadIdx.x] = s;
    __syncthreads();
    for (int stride = 128; stride > 0; stride >>= 1) {
        if (threadIdx.x < stride) sm[threadIdx.x] += sm[threadIdx.x + stride];
        __syncthreads();
    }
    if (threadIdx.x == 0) out[0] = sm[0] / (float)B;
}

extern "C" void kernel_launch(void* const* d_in, const int* in_sizes, int n_in,
                              void* d_out, int out_size, void* d_ws, size_t ws_size,
                              hipStream_t stream) {
    const float* nf    = (const float*)d_in[0];
    const int*   erow  = (const int*)d_in[1];
    const int*   ecol  = (const int*)d_in[2];
    const float* evals = (const float*)d_in[3];
    const int*   a_id  = (const int*)d_in[4];
    const int*   p_id  = (const int*)d_in[5];
    const int*   n_id  = (const int*)d_in[6];

    int N = in_sizes[0] / DDIM;
    int E = in_sizes[1];
    int B = in_sizes[4];
    int NB = (N + BUCKET - 1) / BUCKET;
    int chunk = (E + NBLK - 1) / NBLK;
    int Npad = NB * BUCKET;

    long capl = ((long)E * BUCKET) / N;
    int cap = (int)(capl + capl / 12 + 1024);
    cap = (cap + 63) & ~63;

    size_t regionBytes = (size_t)cap * NB * 8;
    size_t featB32 = (size_t)N * DDIM * 4;
    size_t featB16 = (size_t)N * DDIM * 2;
    size_t subBytes = (size_t)NB * 8 * BUCKET * 4;

    char* w = (char*)d_ws;
    ull*  br     = (ull*)w;           // region A: later fb0+fb1
    char* regAp  = w;                 w += regionBytes;
    unsigned int* bc = (unsigned int*)w;  // region B: bc (4 B), later cw (8 B)
    int2* cw     = (int2*)w;          w += regionBytes;
    float* acc   = (float*)w;         w += featB32;
    int* subcnt  = (int*)w;           w += subBytes;    // becomes pbase in combine
    float* subds = (float*)w;         w += subBytes;
    float* subdsc= (float*)w;         w += subBytes;
    float* inv_c = (float*)w;         w += (size_t)Npad * 4;
    float* inv_r = (float*)w;         w += (size_t)Npad * 4;
    int* rowstart= (int*)w;           w += (size_t)N * 4;
    int* rowend  = (int*)w;           w += (size_t)N * 4;
    int* gfill_r = (int*)w;           w += (size_t)NB * 16 * 4;
    int* gfill_c = (int*)w;           w += (size_t)NB * 16 * 4;
    float* terms = (float*)w;         w += (size_t)B * 4;

    unsigned short* fb0 = (unsigned short*)regAp;             // aliases br (dead after place)
    unsigned short* fb1 = (unsigned short*)(regAp + featB16);

    init_fill_kernel<<<1, 128, 0, stream>>>(gfill_r, gfill_c, NB, cap);
    binning_kernel<<<NBLK, TPB_BIN, 0, stream>>>(erow, ecol, evals, gfill_r, gfill_c,
                                                 br, bc, E, NB, chunk);
    count_kernel<<<NB * 8, TPB_CP, 0, stream>>>(br, bc, gfill_r, gfill_c,
                                                subcnt, subds, subdsc, cap);
    combine_kernel<<<NB, 1024, 0, stream>>>(subcnt, subds, subdsc, rowstart, rowend,
                                            inv_r, inv_c, N, cap);
    place_kernel<<<NB * 8, TPB_CP, 0, stream>>>(br, gfill_r, subcnt, inv_r, inv_c, cw, cap);

    long n2 = (long)N * DDIM / 2;
    cvt_kernel<<<(unsigned)((n2 + 255) / 256), 256, 0, stream>>>(nf, acc, (unsigned int*)fb0, n2);

    unsigned spmmGrid = (unsigned)((N + 3) / 4);   // 4 waves (rows) per 256-thread block
    spmm_f16_kernel<<<spmmGrid, 256, 0, stream>>>(rowstart, rowend, cw, fb0, fb1, acc, N);
    spmm_f16_kernel<<<spmmGrid, 256, 0, stream>>>(rowstart, rowend, cw, fb1, fb0, acc, N);
    spmm_f16_kernel<<<spmmGrid, 256, 0, stream>>>(rowstart, rowend, cw, fb0, fb1, acc, N);

    loss_terms_kernel<<<(unsigned)(((long)B * 64 + 255) / 256), 256, 0, stream>>>(
        acc, a_id, p_id, n_id, terms, B);
    reduce_kernel<<<1, 256, 0, stream>>>(terms, (float*)d_out, B);
}

// Round 12
// 452.316 us; speedup vs baseline: 1.0140x; 1.0140x over previous
//
#include <hip/hip_runtime.h>
#include <math.h>

#define DDIM 64
#define BUCKET 1024             // nodes per binning bucket
#define LRSHIFT 17              // packed: col [0,17), lrow [17,27), val [32,64)
#define CMASK 0x1FFFF
#define LRMASK 0x3FF
#define NBLK 512
#define TPB_BIN 512
#define TPB_CP 512
#define MAXNB 128               // max buckets (NB = ceil(100000/1024) = 98)

typedef unsigned long long ull;
typedef _Float16 half2_t __attribute__((ext_vector_type(2)));

__device__ inline unsigned int bf16_hi(float v) {       // RNE bf16 bits in high 16
    unsigned int a = __float_as_uint(v);
    return (a + 0x7fffu + ((a >> 16) & 1u)) & 0xffff0000u;
}

__device__ inline unsigned int pk_f16x2(float lo, float hi) {
    return __builtin_bit_cast(unsigned int, __builtin_amdgcn_cvt_pkrtz(lo, hi));
}

// ---- init global fill counters (cacheline-padded: stride 16 ints) ----
__global__ void init_fill_kernel(int* __restrict__ gfill_r, int* __restrict__ gfill_c,
                                 int NB, int cap) {
    int k = blockIdx.x * blockDim.x + threadIdx.x;
    if (k < NB) {
        gfill_r[k * 16] = k * cap;
        gfill_c[k * 16] = k * cap;
    }
}

// ---- fused binning: per-wave count, BLOCK-level reserve + place, 2-edge ILP ----
__global__ __launch_bounds__(TPB_BIN)
void binning_kernel(const int* __restrict__ erow, const int* __restrict__ ecol,
                    const float* __restrict__ evals,
                    int* __restrict__ gfill_r, int* __restrict__ gfill_c,
                    ull* __restrict__ br, unsigned int* __restrict__ bc,
                    int E, int NB, int chunk) {
    __shared__ int hr[8][MAXNB];
    __shared__ int hc[8][MAXNB];
    __shared__ int fr[MAXNB];
    __shared__ int fc[MAXNB];
    int t = threadIdx.x;
    int wv = t >> 6;
    for (int k = t; k < 8 * MAXNB; k += TPB_BIN) { (&hr[0][0])[k] = 0; (&hc[0][0])[k] = 0; }
    __syncthreads();
    int lo = blockIdx.x * chunk;             // chunk is even -> lo is even
    int hi = min(E, lo + chunk);
    int npair = (hi - lo) >> 1;
    // phase 1: per-wave count, edge pairs via vector loads
    for (int p = t; p < npair; p += TPB_BIN) {
        int i = lo + 2 * p;
        int2 r2 = *(const int2*)(erow + i);
        int2 c2 = *(const int2*)(ecol + i);
        atomicAdd(&hr[wv][r2.x >> 10], 1);
        atomicAdd(&hr[wv][r2.y >> 10], 1);
        atomicAdd(&hc[wv][c2.x >> 10], 1);
        atomicAdd(&hc[wv][c2.y >> 10], 1);
    }
    if (((hi - lo) & 1) && t == 0) {
        atomicAdd(&hr[wv][erow[hi - 1] >> 10], 1);
        atomicAdd(&hc[wv][ecol[hi - 1] >> 10], 1);
    }
    __syncthreads();
    // phase 2: ONE reservation per (block,bucket)
    if (t < NB) {
        int sr = 0, sc = 0;
        #pragma unroll
        for (int w2 = 0; w2 < 8; w2++) { sr += hr[w2][t]; sc += hc[w2][t]; }
        fr[t] = atomicAdd(&gfill_r[t * 16], sr);
        fc[t] = atomicAdd(&gfill_c[t * 16], sc);
    }
    __syncthreads();
    // phase 3: place edge pairs (two independent atomic->store chains)
    for (int p = t; p < npair; p += TPB_BIN) {
        int i = lo + 2 * p;
        int2 r2 = *(const int2*)(erow + i);
        int2 c2 = *(const int2*)(ecol + i);
        float2 v2 = *(const float2*)(evals + i);
        int pos0 = atomicAdd(&fr[r2.x >> 10], 1);
        int pos1 = atomicAdd(&fr[r2.y >> 10], 1);
        br[pos0] = ((ull)__float_as_uint(v2.x) << 32)
                 | ((ull)(r2.x & 1023) << LRSHIFT) | (unsigned)c2.x;
        br[pos1] = ((ull)__float_as_uint(v2.y) << 32)
                 | ((ull)(r2.y & 1023) << LRSHIFT) | (unsigned)c2.y;
        int pos2 = atomicAdd(&fc[c2.x >> 10], 1);
        int pos3 = atomicAdd(&fc[c2.y >> 10], 1);
        bc[pos2] = bf16_hi(v2.x) | (unsigned)(c2.x & 1023);
        bc[pos3] = bf16_hi(v2.y) | (unsigned)(c2.y & 1023);
    }
    if (((hi - lo) & 1) && t == 0) {
        int i = hi - 1;
        int r = erow[i], c = ecol[i];
        float v = evals[i];
        int pos = atomicAdd(&fr[r >> 10], 1);
        br[pos] = ((ull)__float_as_uint(v) << 32)
                | ((ull)(r & 1023) << LRSHIFT) | (unsigned)c;
        int pos2 = atomicAdd(&fc[c >> 10], 1);
        bc[pos2] = bf16_hi(v) | (unsigned)(c & 1023);
    }
}

// ---- count: block (bucket b, chunk ch) reads its 1/8 edge slice ONCE ----
__global__ __launch_bounds__(TPB_CP)
void count_kernel(const ull* __restrict__ br, const unsigned int* __restrict__ bc,
                  const int* __restrict__ gfill_r, const int* __restrict__ gfill_c,
                  int* __restrict__ subcnt, float* __restrict__ subds,
                  float* __restrict__ subdsc, int cap) {
    __shared__ int cnt[BUCKET];
    __shared__ float ds[BUCKET];
    __shared__ float dsc[BUCKET];
    int b = blockIdx.x >> 3, ch = blockIdx.x & 7;
    int t = threadIdx.x;
    for (int k = t; k < BUCKET; k += TPB_CP) { cnt[k] = 0; ds[k] = 0.0f; dsc[k] = 0.0f; }
    __syncthreads();
    int s = b * cap;
    int e = gfill_r[b * 16];
    int len = ((e - s) + 7) >> 3;
    int cs = s + ch * len, ce = min(e, cs + len);
    for (int i = cs + t; i < ce; i += TPB_CP) {
        ull p = br[i];
        int lr = (int)((p >> LRSHIFT) & LRMASK);
        atomicAdd(&cnt[lr], 1);
        atomicAdd(&ds[lr], __uint_as_float((unsigned)(p >> 32)));
    }
    int e2 = gfill_c[b * 16];
    int len2 = ((e2 - s) + 7) >> 3;
    int cs2 = s + ch * len2, ce2 = min(e2, cs2 + len2);
    for (int i = cs2 + t; i < ce2; i += TPB_CP) {
        unsigned int p = bc[i];
        atomicAdd(&dsc[p & 0x3FFu], __uint_as_float(p & 0xffff0000u));
    }
    __syncthreads();
    size_t base = ((size_t)b * 8 + ch) * BUCKET;
    for (int k = t; k < BUCKET; k += TPB_CP) {
        subcnt[base + k] = cnt[k];
        subds[base + k]  = ds[k];
        subdsc[base + k] = dsc[k];
    }
}

// ---- combine: per-bucket scan -> rowstart/rowend, per-chunk bases, inv_r, inv_c ----
__global__ __launch_bounds__(1024)
void combine_kernel(int* __restrict__ subcnt, const float* __restrict__ subds,
                    const float* __restrict__ subdsc,
                    int* __restrict__ rowstart, int* __restrict__ rowend,
                    float* __restrict__ inv_r, float* __restrict__ inv_c,
                    int N, int cap) {
    __shared__ int tot[BUCKET];
    int b = blockIdx.x, t = threadIdx.x;
    size_t base = (size_t)b * 8 * BUCKET;
    int c8[8];
    int sum = 0;
    #pragma unroll
    for (int c = 0; c < 8; c++) { c8[c] = subcnt[base + c * BUCKET + t]; sum += c8[c]; }
    tot[t] = sum;
    __syncthreads();
    for (int off = 1; off < BUCKET; off <<= 1) {
        int v = (t >= off) ? tot[t - off] : 0;
        __syncthreads();
        tot[t] += v;
        __syncthreads();
    }
    int excl = tot[t] - sum;
    int node = b * BUCKET + t;
    int s = b * cap;
    if (node < N) {
        rowstart[node] = s + excl;
        rowend[node]   = s + excl + sum;
    }
    int run = s + excl;
    #pragma unroll
    for (int c = 0; c < 8; c++) { int v = c8[c]; subcnt[base + c * BUCKET + t] = run; run += v; }
    float d = 0.0f, dc = 0.0f;
    #pragma unroll
    for (int c = 0; c < 8; c++) { d += subds[base + c * BUCKET + t]; dc += subdsc[base + c * BUCKET + t]; }
    inv_r[b * BUCKET + t] = 1.0f / (sqrtf(d) + 1e-8f);
    inv_c[b * BUCKET + t] = 1.0f / (sqrtf(dc) + 1e-8f);
}

// ---- place: ranked placement; weight folded & stored as DUPLICATED f16x2 ----
__global__ __launch_bounds__(TPB_CP)
void place_kernel(const ull* __restrict__ br, const int* __restrict__ gfill_r,
                  const int* __restrict__ pbase, const float* __restrict__ inv_r,
                  const float* __restrict__ inv_c,
                  int2* __restrict__ cw, int cap) {
    __shared__ int fill[BUCKET];
    __shared__ float irs[BUCKET];
    int b = blockIdx.x >> 3, ch = blockIdx.x & 7;
    int t = threadIdx.x;
    size_t pb = ((size_t)b * 8 + ch) * BUCKET;
    for (int k = t; k < BUCKET; k += TPB_CP) {
        fill[k] = pbase[pb + k];
        irs[k]  = inv_r[b * BUCKET + k];
    }
    __syncthreads();
    int s = b * cap;
    int e = gfill_r[b * 16];
    int len = ((e - s) + 7) >> 3;
    int cs = s + ch * len, ce = min(e, cs + len);
    for (int i = cs + t; i < ce; i += TPB_CP) {
        ull p = br[i];
        int c = (int)(p & CMASK);
        int lr = (int)((p >> LRSHIFT) & LRMASK);
        float v = __uint_as_float((unsigned)(p >> 32));
        int pos = atomicAdd(&fill[lr], 1);
        float wv = v * inv_c[c] * irs[lr];
        int2 pk;
        pk.x = c;
        pk.y = (int)pk_f16x2(wv, wv);      // duplicated f16 weight
        cw[pos] = pk;
    }
}

// ---- fused: acc = nf (fp32), fb0 = f16(nf) ----
__global__ void cvt_kernel(const float* __restrict__ src, float* __restrict__ acc,
                           unsigned int* __restrict__ dst, long n2) {
    long i = (long)blockIdx.x * blockDim.x + threadIdx.x;
    if (i < n2) {
        float2 v = ((const float2*)src)[i];
        ((float2*)acc)[i] = v;
        dst[i] = pk_f16x2(v.x, v.y);
    }
}

// ---- SpMM: wave per row, edge pairs, f16 gather + v_pk_fma_f16 ----
__global__ __launch_bounds__(256)
void spmm_f16_kernel(const int* __restrict__ rowstart, const int* __restrict__ rowend,
                     const int2* __restrict__ cw,
                     const unsigned short* __restrict__ fin,
                     unsigned short* __restrict__ fout,
                     float* __restrict__ acc, int N) {
    int wid = blockIdx.x * (blockDim.x >> 6) + (threadIdx.x >> 6);   // row
    if (wid >= N) return;
    int lane = threadIdx.x & 63;
    int g = lane >> 3;          // edge-pair slot 0..7 (16 edges per iteration)
    int h = lane & 7;           // feature chunk (8 f16 = 16 B)
    int s = rowstart[wid], e = rowend[wid];
    half2_t a2[8];              // [0..3]: even-edge partials, [4..7]: odd-edge partials
    #pragma unroll
    for (int k = 0; k < 8; k++) a2[k] = (half2_t)0;

    int nfull = (e - s) >> 4;
    int base = s;
    for (int it = 0; it < nfull; it++, base += 16) {
        int j0 = base + 2 * g;
        int2 p0 = cw[j0];
        int2 p1 = cw[j0 + 1];
        uint4 q0 = ((const uint4*)(fin + ((long)p0.x << 6)))[h];
        uint4 q1 = ((const uint4*)(fin + ((long)p1.x << 6)))[h];
        half2_t w0 = __builtin_bit_cast(half2_t, (unsigned)p0.y);
        half2_t w1 = __builtin_bit_cast(half2_t, (unsigned)p1.y);
        a2[0] += w0 * __builtin_bit_cast(half2_t, q0.x);
        a2[1] += w0 * __builtin_bit_cast(half2_t, q0.y);
        a2[2] += w0 * __builtin_bit_cast(half2_t, q0.z);
        a2[3] += w0 * __builtin_bit_cast(half2_t, q0.w);
        a2[4] += w1 * __builtin_bit_cast(half2_t, q1.x);
        a2[5] += w1 * __builtin_bit_cast(half2_t, q1.y);
        a2[6] += w1 * __builtin_bit_cast(half2_t, q1.z);
        a2[7] += w1 * __builtin_bit_cast(half2_t, q1.w);
    }
    if (base < e) {
        int j0 = base + 2 * g, j1 = j0 + 1;
        int2 p0 = cw[j0];
        int2 p1 = cw[j1];
        int c0 = p0.x & CMASK, c1 = p1.x & CMASK;
        half2_t w0 = (j0 < e) ? __builtin_bit_cast(half2_t, (unsigned)p0.y) : (half2_t)0;
        half2_t w1 = (j1 < e) ? __builtin_bit_cast(half2_t, (unsigned)p1.y) : (half2_t)0;
        uint4 q0 = ((const uint4*)(fin + ((long)c0 << 6)))[h];
        uint4 q1 = ((const uint4*)(fin + ((long)c1 << 6)))[h];
        a2[0] += w0 * __builtin_bit_cast(half2_t, q0.x);
        a2[1] += w0 * __builtin_bit_cast(half2_t, q0.y);
        a2[2] += w0 * __builtin_bit_cast(half2_t, q0.z);
        a2[3] += w0 * __builtin_bit_cast(half2_t, q0.w);
        a2[4] += w1 * __builtin_bit_cast(half2_t, q1.x);
        a2[5] += w1 * __builtin_bit_cast(half2_t, q1.y);
        a2[6] += w1 * __builtin_bit_cast(half2_t, q1.z);
        a2[7] += w1 * __builtin_bit_cast(half2_t, q1.w);
    }

    float a[8];
    #pragma unroll
    for (int k = 0; k < 4; k++) {
        a[2 * k]     = (float)a2[k][0] + (float)a2[k + 4][0];
        a[2 * k + 1] = (float)a2[k][1] + (float)a2[k + 4][1];
    }
    #pragma unroll
    for (int k = 0; k < 8; k++) {
        a[k] += __shfl_xor(a[k], 8);
        a[k] += __shfl_xor(a[k], 16);
        a[k] += __shfl_xor(a[k], 32);
    }
    float ss = 0.0f;
    #pragma unroll
    for (int k = 0; k < 8; k++) ss += a[k] * a[k];
    ss += __shfl_xor(ss, 1);
    ss += __shfl_xor(ss, 2);
    ss += __shfl_xor(ss, 4);
    float s2 = 1.0f / fmaxf(sqrtf(ss), 1e-12f);
    if (g == 0) {
        uint4 o;
        o.x = pk_f16x2(a[0], a[1]);
        o.y = pk_f16x2(a[2], a[3]);
        o.z = pk_f16x2(a[4], a[5]);
        o.w = pk_f16x2(a[6], a[7]);
        ((uint4*)(fout + ((long)wid << 6)))[h] = o;
        float4* ap = (float4*)(acc + ((long)wid << 6)) + (h << 1);
        float4 c0 = ap[0], c1 = ap[1];
        c0.x += a[0] * s2; c0.y += a[1] * s2; c0.z += a[2] * s2; c0.w += a[3] * s2;
        c1.x += a[4] * s2; c1.y += a[5] * s2; c1.z += a[6] * s2; c1.w += a[7] * s2;
        ap[0] = c0;
        ap[1] = c1;
    }
}

// ---- BPR loss ----
__global__ void loss_terms_kernel(const float* __restrict__ acc,
                                  const int* __restrict__ a_id, const int* __restrict__ p_id,
                                  const int* __restrict__ n_id,
                                  float* __restrict__ terms, int B) {
    long gid = (long)blockIdx.x * blockDim.x + threadIdx.x;
    int b = (int)(gid >> 6);
    int lane = threadIdx.x & 63;
    if (b < B) {
        int ia = a_id[b], ip = p_id[b], in2 = n_id[b];
        float a = acc[(long)ia * DDIM + lane];
        float p = acc[(long)ip * DDIM + lane];
        float n = acc[(long)in2 * DDIM + lane];
        float dp = a * p, dn = a * n;
        #pragma unroll
        for (int off = 1; off < 64; off <<= 1) { dp += __shfl_xor(dp, off); dn += __shfl_xor(dn, off); }
        if (lane == 0) {
            float x = (dp - dn) * 0.0625f;   // node_rep = acc/4 -> preds scale 1/16
            terms[b] = fmaxf(-x, 0.0f) + log1pf(expf(-fabsf(x)));
        }
    }
}

__global__ void reduce_kernel(const float* __restrict__ terms, float* __restrict__ out, int B) {
    __shared__ float sm[256];
    float s = 0.0f;
    for (int i = threadIdx.x; i < B; i += 256) s += terms[i];
    sm[threadIdx.x] = s;
    __syncthreads();
    for (int stride = 128; stride > 0; stride >>= 1) {
        if (threadIdx.x < stride) sm[threadIdx.x] += sm[threadIdx.x + stride];
        __syncthreads();
    }
    if (threadIdx.x == 0) out[0] = sm[0] / (float)B;
}

extern "C" void kernel_launch(void* const* d_in, const int* in_sizes, int n_in,
                              void* d_out, int out_size, void* d_ws, size_t ws_size,
                              hipStream_t stream) {
    const float* nf    = (const float*)d_in[0];
    const int*   erow  = (const int*)d_in[1];
    const int*   ecol  = (const int*)d_in[2];
    const float* evals = (const float*)d_in[3];
    const int*   a_id  = (const int*)d_in[4];
    const int*   p_id  = (const int*)d_in[5];
    const int*   n_id  = (const int*)d_in[6];

    int N = in_sizes[0] / DDIM;
    int E = in_sizes[1];
    int B = in_sizes[4];
    int NB = (N + BUCKET - 1) / BUCKET;
    int chunk = (((E + NBLK - 1) / NBLK) + 1) & ~1;   // even chunk -> aligned pair loads
    int Npad = NB * BUCKET;

    long capl = ((long)E * BUCKET) / N;
    int cap = (int)(capl + capl / 12 + 1024);
    cap = (cap + 63) & ~63;

    size_t regionBytes = (size_t)cap * NB * 8;
    size_t featB32 = (size_t)N * DDIM * 4;
    size_t featB16 = (size_t)N * DDIM * 2;
    size_t subBytes = (size_t)NB * 8 * BUCKET * 4;

    char* w = (char*)d_ws;
    ull*  br     = (ull*)w;           // region A: later fb0+fb1
    char* regAp  = w;                 w += regionBytes;
    unsigned int* bc = (unsigned int*)w;  // region B: bc (4 B), later cw (8 B)
    int2* cw     = (int2*)w;          w += regionBytes;
    float* acc   = (float*)w;         w += featB32;
    int* subcnt  = (int*)w;           w += subBytes;    // becomes pbase in combine
    float* subds = (float*)w;         w += subBytes;
    float* subdsc= (float*)w;         w += subBytes;
    float* inv_c = (float*)w;         w += (size_t)Npad * 4;
    float* inv_r = (float*)w;         w += (size_t)Npad * 4;
    int* rowstart= (int*)w;           w += (size_t)N * 4;
    int* rowend  = (int*)w;           w += (size_t)N * 4;
    int* gfill_r = (int*)w;           w += (size_t)NB * 16 * 4;
    int* gfill_c = (int*)w;           w += (size_t)NB * 16 * 4;
    float* terms = (float*)w;         w += (size_t)B * 4;

    unsigned short* fb0 = (unsigned short*)regAp;             // aliases br (dead after place)
    unsigned short* fb1 = (unsigned short*)(regAp + featB16);

    init_fill_kernel<<<1, 128, 0, stream>>>(gfill_r, gfill_c, NB, cap);
    binning_kernel<<<NBLK, TPB_BIN, 0, stream>>>(erow, ecol, evals, gfill_r, gfill_c,
                                                 br, bc, E, NB, chunk);
    count_kernel<<<NB * 8, TPB_CP, 0, stream>>>(br, bc, gfill_r, gfill_c,
                                                subcnt, subds, subdsc, cap);
    combine_kernel<<<NB, 1024, 0, stream>>>(subcnt, subds, subdsc, rowstart, rowend,
                                            inv_r, inv_c, N, cap);
    place_kernel<<<NB * 8, TPB_CP, 0, stream>>>(br, gfill_r, subcnt, inv_r, inv_c, cw, cap);

    long n2 = (long)N * DDIM / 2;
    cvt_kernel<<<(unsigned)((n2 + 255) / 256), 256, 0, stream>>>(nf, acc, (unsigned int*)fb0, n2);

    unsigned spmmGrid = (unsigned)((N + 3) / 4);   // 4 waves (rows) per 256-thread block
    spmm_f16_kernel<<<spmmGrid, 256, 0, stream>>>(rowstart, rowend, cw, fb0, fb1, acc, N);
    spmm_f16_kernel<<<spmmGrid, 256, 0, stream>>>(rowstart, rowend, cw, fb1, fb0, acc, N);
    spmm_f16_kernel<<<spmmGrid, 256, 0, stream>>>(rowstart, rowend, cw, fb0, fb1, acc, N);

    loss_terms_kernel<<<(unsigned)(((long)B * 64 + 255) / 256), 256, 0, stream>>>(
        acc, a_id, p_id, n_id, terms, B);
    reduce_kernel<<<1, 256, 0, stream>>>(terms, (float*)d_out, B);
}

// Round 13
// 436.432 us; speedup vs baseline: 1.0509x; 1.0364x over previous
//
#include <hip/hip_runtime.h>
#include <math.h>

#define DDIM 64
#define BUCKET 1024             // nodes per binning bucket
#define LRSHIFT 17              // packed: col [0,17), lrow [17,27), val [32,64)
#define CMASK 0x1FFFF
#define LRMASK 0x3FF
#define NBLK 512
#define TPB_BIN 512
#define TPB_CP 512
#define MAXNB 128               // max buckets (NB = ceil(100000/1024) = 98)

typedef unsigned long long ull;
typedef _Float16 half2_t __attribute__((ext_vector_type(2)));

__device__ inline unsigned int bf16_hi(float v) {       // RNE bf16 bits in high 16
    unsigned int a = __float_as_uint(v);
    return (a + 0x7fffu + ((a >> 16) & 1u)) & 0xffff0000u;
}

__device__ inline unsigned int pk_f16x2(float lo, float hi) {
    return __builtin_bit_cast(unsigned int, __builtin_amdgcn_cvt_pkrtz(lo, hi));
}

// ---- init global fill counters (cacheline-padded: stride 16 ints) ----
__global__ void init_fill_kernel(int* __restrict__ gfill_r, int* __restrict__ gfill_c,
                                 int NB, int cap) {
    int k = blockIdx.x * blockDim.x + threadIdx.x;
    if (k < NB) {
        gfill_r[k * 16] = k * cap;
        gfill_c[k * 16] = k * cap;
    }
}

// ---- fused binning: per-wave count, BLOCK-level reserve + place, 4-edge ILP ----
__global__ __launch_bounds__(TPB_BIN)
void binning_kernel(const int* __restrict__ erow, const int* __restrict__ ecol,
                    const float* __restrict__ evals,
                    int* __restrict__ gfill_r, int* __restrict__ gfill_c,
                    ull* __restrict__ br, unsigned int* __restrict__ bc,
                    int E, int NB, int chunk) {
    __shared__ int hr[8][MAXNB];
    __shared__ int hc[8][MAXNB];
    __shared__ int fr[MAXNB];
    __shared__ int fc[MAXNB];
    int t = threadIdx.x;
    int wv = t >> 6;
    for (int k = t; k < 8 * MAXNB; k += TPB_BIN) { (&hr[0][0])[k] = 0; (&hc[0][0])[k] = 0; }
    __syncthreads();
    int lo = blockIdx.x * chunk;             // chunk multiple of 4 -> lo 16B-aligned
    int hi = min(E, lo + chunk);
    int nq = (hi - lo) >> 2;
    int rem = (hi - lo) & 3;
    // phase 1: per-wave count, 4 edges per thread
    for (int p = t; p < nq; p += TPB_BIN) {
        int i = lo + 4 * p;
        int4 r4 = *(const int4*)(erow + i);
        int4 c4 = *(const int4*)(ecol + i);
        atomicAdd(&hr[wv][r4.x >> 10], 1);
        atomicAdd(&hr[wv][r4.y >> 10], 1);
        atomicAdd(&hr[wv][r4.z >> 10], 1);
        atomicAdd(&hr[wv][r4.w >> 10], 1);
        atomicAdd(&hc[wv][c4.x >> 10], 1);
        atomicAdd(&hc[wv][c4.y >> 10], 1);
        atomicAdd(&hc[wv][c4.z >> 10], 1);
        atomicAdd(&hc[wv][c4.w >> 10], 1);
    }
    if (t == 0) {
        for (int i = hi - rem; i < hi; i++) {
            atomicAdd(&hr[0][erow[i] >> 10], 1);
            atomicAdd(&hc[0][ecol[i] >> 10], 1);
        }
    }
    __syncthreads();
    // phase 2: ONE reservation per (block,bucket) -> long output runs
    if (t < NB) {
        int sr = 0, sc = 0;
        #pragma unroll
        for (int w2 = 0; w2 < 8; w2++) { sr += hr[w2][t]; sc += hc[w2][t]; }
        fr[t] = atomicAdd(&gfill_r[t * 16], sr);
        fc[t] = atomicAdd(&gfill_c[t * 16], sc);
    }
    __syncthreads();
    // phase 3: place 4 edges per thread (4 independent atomic->store chains)
    for (int p = t; p < nq; p += TPB_BIN) {
        int i = lo + 4 * p;
        int4 r4 = *(const int4*)(erow + i);
        int4 c4 = *(const int4*)(ecol + i);
        float4 v4 = *(const float4*)(evals + i);
        int pos0 = atomicAdd(&fr[r4.x >> 10], 1);
        int pos1 = atomicAdd(&fr[r4.y >> 10], 1);
        int pos2 = atomicAdd(&fr[r4.z >> 10], 1);
        int pos3 = atomicAdd(&fr[r4.w >> 10], 1);
        br[pos0] = ((ull)__float_as_uint(v4.x) << 32) | ((ull)(r4.x & 1023) << LRSHIFT) | (unsigned)c4.x;
        br[pos1] = ((ull)__float_as_uint(v4.y) << 32) | ((ull)(r4.y & 1023) << LRSHIFT) | (unsigned)c4.y;
        br[pos2] = ((ull)__float_as_uint(v4.z) << 32) | ((ull)(r4.z & 1023) << LRSHIFT) | (unsigned)c4.z;
        br[pos3] = ((ull)__float_as_uint(v4.w) << 32) | ((ull)(r4.w & 1023) << LRSHIFT) | (unsigned)c4.w;
        int q0 = atomicAdd(&fc[c4.x >> 10], 1);
        int q1 = atomicAdd(&fc[c4.y >> 10], 1);
        int q2 = atomicAdd(&fc[c4.z >> 10], 1);
        int q3 = atomicAdd(&fc[c4.w >> 10], 1);
        bc[q0] = bf16_hi(v4.x) | (unsigned)(c4.x & 1023);
        bc[q1] = bf16_hi(v4.y) | (unsigned)(c4.y & 1023);
        bc[q2] = bf16_hi(v4.z) | (unsigned)(c4.z & 1023);
        bc[q3] = bf16_hi(v4.w) | (unsigned)(c4.w & 1023);
    }
    if (t == 0) {
        for (int i = hi - rem; i < hi; i++) {
            int r = erow[i], c = ecol[i];
            float v = evals[i];
            int pos = atomicAdd(&fr[r >> 10], 1);
            br[pos] = ((ull)__float_as_uint(v) << 32) | ((ull)(r & 1023) << LRSHIFT) | (unsigned)c;
            int pos2 = atomicAdd(&fc[c >> 10], 1);
            bc[pos2] = bf16_hi(v) | (unsigned)(c & 1023);
        }
    }
}

// ---- count: block (bucket b, chunk ch) reads its 1/8 edge slice ONCE, 2-edge ILP ----
__global__ __launch_bounds__(TPB_CP)
void count_kernel(const ull* __restrict__ br, const unsigned int* __restrict__ bc,
                  const int* __restrict__ gfill_r, const int* __restrict__ gfill_c,
                  int* __restrict__ subcnt, float* __restrict__ subds,
                  float* __restrict__ subdsc, int cap) {
    __shared__ int cnt[BUCKET];
    __shared__ float ds[BUCKET];
    __shared__ float dsc[BUCKET];
    int b = blockIdx.x >> 3, ch = blockIdx.x & 7;
    int t = threadIdx.x;
    for (int k = t; k < BUCKET; k += TPB_CP) { cnt[k] = 0; ds[k] = 0.0f; dsc[k] = 0.0f; }
    __syncthreads();
    int s = b * cap;                              // cap mult of 64 -> s even
    int e = gfill_r[b * 16];
    int len = ((((e - s) + 7) >> 3) + 1) & ~1;    // even slice length
    int cs = s + ch * len, ce = min(e, cs + len);
    int m = cs + ((ce - cs) & ~1);
    for (int i = cs + 2 * t; i < m; i += 2 * TPB_CP) {
        ull p0 = br[i];
        ull p1 = br[i + 1];
        int lr0 = (int)((p0 >> LRSHIFT) & LRMASK);
        int lr1 = (int)((p1 >> LRSHIFT) & LRMASK);
        atomicAdd(&cnt[lr0], 1);
        atomicAdd(&cnt[lr1], 1);
        atomicAdd(&ds[lr0], __uint_as_float((unsigned)(p0 >> 32)));
        atomicAdd(&ds[lr1], __uint_as_float((unsigned)(p1 >> 32)));
    }
    if (t == 0 && m < ce) {
        ull p = br[m];
        int lr = (int)((p >> LRSHIFT) & LRMASK);
        atomicAdd(&cnt[lr], 1);
        atomicAdd(&ds[lr], __uint_as_float((unsigned)(p >> 32)));
    }
    int e2 = gfill_c[b * 16];
    int len2 = ((((e2 - s) + 7) >> 3) + 1) & ~1;
    int cs2 = s + ch * len2, ce2 = min(e2, cs2 + len2);
    int m2 = cs2 + ((ce2 - cs2) & ~1);
    for (int i = cs2 + 2 * t; i < m2; i += 2 * TPB_CP) {
        uint2 p = *(const uint2*)(bc + i);
        atomicAdd(&dsc[p.x & 0x3FFu], __uint_as_float(p.x & 0xffff0000u));
        atomicAdd(&dsc[p.y & 0x3FFu], __uint_as_float(p.y & 0xffff0000u));
    }
    if (t == 0 && m2 < ce2) {
        unsigned int p = bc[m2];
        atomicAdd(&dsc[p & 0x3FFu], __uint_as_float(p & 0xffff0000u));
    }
    __syncthreads();
    size_t base = ((size_t)b * 8 + ch) * BUCKET;
    for (int k = t; k < BUCKET; k += TPB_CP) {
        subcnt[base + k] = cnt[k];
        subds[base + k]  = ds[k];
        subdsc[base + k] = dsc[k];
    }
}

// ---- combine: even-rounded scan -> even rowstart, per-chunk bases, inv_r, inv_c ----
__global__ __launch_bounds__(1024)
void combine_kernel(int* __restrict__ subcnt, const float* __restrict__ subds,
                    const float* __restrict__ subdsc,
                    int* __restrict__ rowstart, int* __restrict__ rowend,
                    float* __restrict__ inv_r, float* __restrict__ inv_c,
                    int N, int cap) {
    __shared__ int tot[BUCKET];
    int b = blockIdx.x, t = threadIdx.x;
    size_t base = (size_t)b * 8 * BUCKET;
    int c8[8];
    int sum = 0;
    #pragma unroll
    for (int c = 0; c < 8; c++) { c8[c] = subcnt[base + c * BUCKET + t]; sum += c8[c]; }
    int sum2 = (sum + 1) & ~1;           // even-rounded slot count -> even row starts
    tot[t] = sum2;
    __syncthreads();
    for (int off = 1; off < BUCKET; off <<= 1) {
        int v = (t >= off) ? tot[t - off] : 0;
        __syncthreads();
        tot[t] += v;
        __syncthreads();
    }
    int excl = tot[t] - sum2;
    int node = b * BUCKET + t;
    int s = b * cap;
    if (node < N) {
        rowstart[node] = s + excl;
        rowend[node]   = s + excl + sum;
    }
    int run = s + excl;
    #pragma unroll
    for (int c = 0; c < 8; c++) { int v = c8[c]; subcnt[base + c * BUCKET + t] = run; run += v; }
    float d = 0.0f, dc = 0.0f;
    #pragma unroll
    for (int c = 0; c < 8; c++) { d += subds[base + c * BUCKET + t]; dc += subdsc[base + c * BUCKET + t]; }
    inv_r[b * BUCKET + t] = 1.0f / (sqrtf(d) + 1e-8f);
    inv_c[b * BUCKET + t] = 1.0f / (sqrtf(dc) + 1e-8f);
}

// ---- place: ranked placement, 2-edge ILP; weight folded & stored dup f16x2 ----
__global__ __launch_bounds__(TPB_CP)
void place_kernel(const ull* __restrict__ br, const int* __restrict__ gfill_r,
                  const int* __restrict__ pbase, const float* __restrict__ inv_r,
                  const float* __restrict__ inv_c,
                  int2* __restrict__ cw, int cap) {
    __shared__ int fill[BUCKET];
    __shared__ float irs[BUCKET];
    int b = blockIdx.x >> 3, ch = blockIdx.x & 7;
    int t = threadIdx.x;
    size_t pb = ((size_t)b * 8 + ch) * BUCKET;
    for (int k = t; k < BUCKET; k += TPB_CP) {
        fill[k] = pbase[pb + k];
        irs[k]  = inv_r[b * BUCKET + k];
    }
    __syncthreads();
    int s = b * cap;
    int e = gfill_r[b * 16];
    int len = ((((e - s) + 7) >> 3) + 1) & ~1;
    int cs = s + ch * len, ce = min(e, cs + len);
    int m = cs + ((ce - cs) & ~1);
    for (int i = cs + 2 * t; i < m; i += 2 * TPB_CP) {
        ull p0 = br[i];
        ull p1 = br[i + 1];
        int c0 = (int)(p0 & CMASK), c1 = (int)(p1 & CMASK);
        int lr0 = (int)((p0 >> LRSHIFT) & LRMASK);
        int lr1 = (int)((p1 >> LRSHIFT) & LRMASK);
        float v0 = __uint_as_float((unsigned)(p0 >> 32));
        float v1 = __uint_as_float((unsigned)(p1 >> 32));
        int pos0 = atomicAdd(&fill[lr0], 1);
        int pos1 = atomicAdd(&fill[lr1], 1);
        float w0 = v0 * inv_c[c0] * irs[lr0];
        float w1 = v1 * inv_c[c1] * irs[lr1];
        int2 pk0; pk0.x = c0; pk0.y = (int)pk_f16x2(w0, w0);
        int2 pk1; pk1.x = c1; pk1.y = (int)pk_f16x2(w1, w1);
        cw[pos0] = pk0;
        cw[pos1] = pk1;
    }
    if (t == 0 && m < ce) {
        ull p = br[m];
        int c = (int)(p & CMASK);
        int lr = (int)((p >> LRSHIFT) & LRMASK);
        float v = __uint_as_float((unsigned)(p >> 32));
        int pos = atomicAdd(&fill[lr], 1);
        float wv = v * inv_c[c] * irs[lr];
        int2 pk; pk.x = c; pk.y = (int)pk_f16x2(wv, wv);
        cw[pos] = pk;
    }
}

// ---- fused: acc = nf (fp32), fb0 = f16(nf); 4 floats/thread ----
__global__ void cvt_kernel(const float* __restrict__ src, float* __restrict__ acc,
                           unsigned int* __restrict__ dst, long n4) {
    long i = (long)blockIdx.x * blockDim.x + threadIdx.x;
    if (i < n4) {
        float4 v = ((const float4*)src)[i];
        ((float4*)acc)[i] = v;
        uint2 o;
        o.x = pk_f16x2(v.x, v.y);
        o.y = pk_f16x2(v.z, v.w);
        ((uint2*)dst)[i] = o;
    }
}

// ---- SpMM: wave per row, edge pairs via ONE int4 cw load, v_pk_fma_f16 ----
__global__ __launch_bounds__(256)
void spmm_f16_kernel(const int* __restrict__ rowstart, const int* __restrict__ rowend,
                     const int2* __restrict__ cw,
                     const unsigned short* __restrict__ fin,
                     unsigned short* __restrict__ fout,
                     float* __restrict__ acc, int N) {
    int wid = blockIdx.x * (blockDim.x >> 6) + (threadIdx.x >> 6);   // row
    if (wid >= N) return;
    int lane = threadIdx.x & 63;
    int g = lane >> 3;          // edge-pair slot 0..7 (16 edges per iteration)
    int h = lane & 7;           // feature chunk (8 f16 = 16 B)
    int s = rowstart[wid], e = rowend[wid];   // s is even -> int4-aligned cw pairs
    half2_t a2[8];              // [0..3]: even-edge partials, [4..7]: odd-edge partials
    #pragma unroll
    for (int k = 0; k < 8; k++) a2[k] = (half2_t)0;

    int nfull = (e - s) >> 4;
    int base = s;
    for (int it = 0; it < nfull; it++, base += 16) {
        int j0 = base + 2 * g;
        int4 p = *(const int4*)(cw + j0);     // c0, w0, c1, w1
        uint4 q0 = ((const uint4*)(fin + ((long)p.x << 6)))[h];
        uint4 q1 = ((const uint4*)(fin + ((long)p.z << 6)))[h];
        half2_t w0 = __builtin_bit_cast(half2_t, (unsigned)p.y);
        half2_t w1 = __builtin_bit_cast(half2_t, (unsigned)p.w);
        a2[0] += w0 * __builtin_bit_cast(half2_t, q0.x);
        a2[1] += w0 * __builtin_bit_cast(half2_t, q0.y);
        a2[2] += w0 * __builtin_bit_cast(half2_t, q0.z);
        a2[3] += w0 * __builtin_bit_cast(half2_t, q0.w);
        a2[4] += w1 * __builtin_bit_cast(half2_t, q1.x);
        a2[5] += w1 * __builtin_bit_cast(half2_t, q1.y);
        a2[6] += w1 * __builtin_bit_cast(half2_t, q1.z);
        a2[7] += w1 * __builtin_bit_cast(half2_t, q1.w);
    }
    if (base < e) {
        int j0 = base + 2 * g, j1 = j0 + 1;
        int4 p = *(const int4*)(cw + j0);     // in-region (padded); mask validity
        int c0 = p.x & CMASK, c1 = p.z & CMASK;
        half2_t w0 = (j0 < e) ? __builtin_bit_cast(half2_t, (unsigned)p.y) : (half2_t)0;
        half2_t w1 = (j1 < e) ? __builtin_bit_cast(half2_t, (unsigned)p.w) : (half2_t)0;
        uint4 q0 = ((const uint4*)(fin + ((long)c0 << 6)))[h];
        uint4 q1 = ((const uint4*)(fin + ((long)c1 << 6)))[h];
        a2[0] += w0 * __builtin_bit_cast(half2_t, q0.x);
        a2[1] += w0 * __builtin_bit_cast(half2_t, q0.y);
        a2[2] += w0 * __builtin_bit_cast(half2_t, q0.z);
        a2[3] += w0 * __builtin_bit_cast(half2_t, q0.w);
        a2[4] += w1 * __builtin_bit_cast(half2_t, q1.x);
        a2[5] += w1 * __builtin_bit_cast(half2_t, q1.y);
        a2[6] += w1 * __builtin_bit_cast(half2_t, q1.z);
        a2[7] += w1 * __builtin_bit_cast(half2_t, q1.w);
    }

    float a[8];
    #pragma unroll
    for (int k = 0; k < 4; k++) {
        a[2 * k]     = (float)a2[k][0] + (float)a2[k + 4][0];
        a[2 * k + 1] = (float)a2[k][1] + (float)a2[k + 4][1];
    }
    #pragma unroll
    for (int k = 0; k < 8; k++) {
        a[k] += __shfl_xor(a[k], 8);
        a[k] += __shfl_xor(a[k], 16);
        a[k] += __shfl_xor(a[k], 32);
    }
    float ss = 0.0f;
    #pragma unroll
    for (int k = 0; k < 8; k++) ss += a[k] * a[k];
    ss += __shfl_xor(ss, 1);
    ss += __shfl_xor(ss, 2);
    ss += __shfl_xor(ss, 4);
    float s2 = 1.0f / fmaxf(sqrtf(ss), 1e-12f);
    if (g == 0) {
        uint4 o;
        o.x = pk_f16x2(a[0], a[1]);
        o.y = pk_f16x2(a[2], a[3]);
        o.z = pk_f16x2(a[4], a[5]);
        o.w = pk_f16x2(a[6], a[7]);
        ((uint4*)(fout + ((long)wid << 6)))[h] = o;
        float4* ap = (float4*)(acc + ((long)wid << 6)) + (h << 1);
        float4 c0 = ap[0], c1 = ap[1];
        c0.x += a[0] * s2; c0.y += a[1] * s2; c0.z += a[2] * s2; c0.w += a[3] * s2;
        c1.x += a[4] * s2; c1.y += a[5] * s2; c1.z += a[6] * s2; c1.w += a[7] * s2;
        ap[0] = c0;
        ap[1] = c1;
    }
}

// ---- BPR loss ----
__global__ void loss_terms_kernel(const float* __restrict__ acc,
                                  const int* __restrict__ a_id, const int* __restrict__ p_id,
                                  const int* __restrict__ n_id,
                                  float* __restrict__ terms, int B) {
    long gid = (long)blockIdx.x * blockDim.x + threadIdx.x;
    int b = (int)(gid >> 6);
    int lane = threadIdx.x & 63;
    if (b < B) {
        int ia = a_id[b], ip = p_id[b], in2 = n_id[b];
        float a = acc[(long)ia * DDIM + lane];
        float p = acc[(long)ip * DDIM + lane];
        float n = acc[(long)in2 * DDIM + lane];
        float dp = a * p, dn = a * n;
        #pragma unroll
        for (int off = 1; off < 64; off <<= 1) { dp += __shfl_xor(dp, off); dn += __shfl_xor(dn, off); }
        if (lane == 0) {
            float x = (dp - dn) * 0.0625f;   // node_rep = acc/4 -> preds scale 1/16
            terms[b] = fmaxf(-x, 0.0f) + log1pf(expf(-fabsf(x)));
        }
    }
}

__global__ void reduce_kernel(const float* __restrict__ terms, float* __restrict__ out, int B) {
    __shared__ float sm[256];
    float s = 0.0f;
    for (int i = threadIdx.x; i < B; i += 256) s += terms[i];
    sm[threadIdx.x] = s;
    __syncthreads();
    for (int stride = 128; stride > 0; stride >>= 1) {
        if (threadIdx.x < stride) sm[threadIdx.x] += sm[threadIdx.x + stride];
        __syncthreads();
    }
    if (threadIdx.x == 0) out[0] = sm[0] / (float)B;
}

extern "C" void kernel_launch(void* const* d_in, const int* in_sizes, int n_in,
                              void* d_out, int out_size, void* d_ws, size_t ws_size,
                              hipStream_t stream) {
    const float* nf    = (const float*)d_in[0];
    const int*   erow  = (const int*)d_in[1];
    const int*   ecol  = (const int*)d_in[2];
    const float* evals = (const float*)d_in[3];
    const int*   a_id  = (const int*)d_in[4];
    const int*   p_id  = (const int*)d_in[5];
    const int*   n_id  = (const int*)d_in[6];

    int N = in_sizes[0] / DDIM;
    int E = in_sizes[1];
    int B = in_sizes[4];
    int NB = (N + BUCKET - 1) / BUCKET;
    int chunk = (((E + NBLK - 1) / NBLK) + 3) & ~3;   // multiple of 4 -> aligned quad loads
    int Npad = NB * BUCKET;

    // bucket capacity: mean + ~8.3% + 2048 (even-rounding pad + >10 sigma)
    long capl = ((long)E * BUCKET) / N;
    int cap = (int)(capl + capl / 12 + 2048);
    cap = (cap + 63) & ~63;

    size_t regionBytes = (size_t)cap * NB * 8;
    size_t featB32 = (size_t)N * DDIM * 4;
    size_t featB16 = (size_t)N * DDIM * 2;
    size_t subBytes = (size_t)NB * 8 * BUCKET * 4;

    char* w = (char*)d_ws;
    ull*  br     = (ull*)w;           // region A: later fb0+fb1
    char* regAp  = w;                 w += regionBytes;
    unsigned int* bc = (unsigned int*)w;  // region B: bc (4 B), later cw (8 B)
    int2* cw     = (int2*)w;          w += regionBytes;
    float* acc   = (float*)w;         w += featB32;
    int* subcnt  = (int*)w;           w += subBytes;    // becomes pbase in combine
    float* subds = (float*)w;         w += subBytes;
    float* subdsc= (float*)w;         w += subBytes;
    float* inv_c = (float*)w;         w += (size_t)Npad * 4;
    float* inv_r = (float*)w;         w += (size_t)Npad * 4;
    int* rowstart= (int*)w;           w += (size_t)N * 4;
    int* rowend  = (int*)w;           w += (size_t)N * 4;
    int* gfill_r = (int*)w;           w += (size_t)NB * 16 * 4;
    int* gfill_c = (int*)w;           w += (size_t)NB * 16 * 4;
    float* terms = (float*)w;         w += (size_t)B * 4;

    unsigned short* fb0 = (unsigned short*)regAp;             // aliases br (dead after place)
    unsigned short* fb1 = (unsigned short*)(regAp + featB16);

    init_fill_kernel<<<1, 128, 0, stream>>>(gfill_r, gfill_c, NB, cap);
    binning_kernel<<<NBLK, TPB_BIN, 0, stream>>>(erow, ecol, evals, gfill_r, gfill_c,
                                                 br, bc, E, NB, chunk);
    count_kernel<<<NB * 8, TPB_CP, 0, stream>>>(br, bc, gfill_r, gfill_c,
                                                subcnt, subds, subdsc, cap);
    combine_kernel<<<NB, 1024, 0, stream>>>(subcnt, subds, subdsc, rowstart, rowend,
                                            inv_r, inv_c, N, cap);
    place_kernel<<<NB * 8, TPB_CP, 0, stream>>>(br, gfill_r, subcnt, inv_r, inv_c, cw, cap);

    long n4 = (long)N * DDIM / 4;
    cvt_kernel<<<(unsigned)((n4 + 255) / 256), 256, 0, stream>>>(nf, acc, (unsigned int*)fb0, n4);

    unsigned spmmGrid = (unsigned)((N + 3) / 4);   // 4 waves (rows) per 256-thread block
    spmm_f16_kernel<<<spmmGrid, 256, 0, stream>>>(rowstart, rowend, cw, fb0, fb1, acc, N);
    spmm_f16_kernel<<<spmmGrid, 256, 0, stream>>>(rowstart, rowend, cw, fb1, fb0, acc, N);
    spmm_f16_kernel<<<spmmGrid, 256, 0, stream>>>(rowstart, rowend, cw, fb0, fb1, acc, N);

    loss_terms_kernel<<<(unsigned)(((long)B * 64 + 255) / 256), 256, 0, stream>>>(
        acc, a_id, p_id, n_id, terms, B);
    reduce_kernel<<<1, 256, 0, stream>>>(terms, (float*)d_out, B);
}

// Round 14
// 425.062 us; speedup vs baseline: 1.0790x; 1.0268x over previous
//
#include <hip/hip_runtime.h>
#include <math.h>

#define DDIM 64
#define BUCKET 1024             // nodes per binning bucket
#define LRSHIFT 17              // br-packed: col [0,17), lrow [17,27), val [32,64)
#define CMASK 0x1FFFF
#define LRMASK 0x3FF
#define NBLK 512
#define TPB_BIN 512
#define TPB_CP 512
#define MAXNB 128               // max buckets (NB = ceil(100000/1024) = 98)

typedef unsigned long long ull;
typedef _Float16 half2_t __attribute__((ext_vector_type(2)));

__device__ inline unsigned int bf16_hi(float v) {       // RNE bf16 bits in high 16
    unsigned int a = __float_as_uint(v);
    return (a + 0x7fffu + ((a >> 16) & 1u)) & 0xffff0000u;
}

__device__ inline unsigned int pk_f16x2(float lo, float hi) {
    return __builtin_bit_cast(unsigned int, __builtin_amdgcn_cvt_pkrtz(lo, hi));
}

__device__ inline half2_t dup_lo16(unsigned int s) {    // (s&0xFFFF) in both halves
    return __builtin_bit_cast(half2_t, __builtin_amdgcn_perm(0u, s, 0x01000100u));
}

// ---- init global fill counters (cacheline-padded: stride 16 ints) ----
__global__ void init_fill_kernel(int* __restrict__ gfill_r, int* __restrict__ gfill_c,
                                 int NB, int cap) {
    int k = blockIdx.x * blockDim.x + threadIdx.x;
    if (k < NB) {
        gfill_r[k * 16] = k * cap;
        gfill_c[k * 16] = k * cap;
    }
}

// ---- fused binning: per-wave count, BLOCK-level reserve + place, 4-edge ILP ----
__global__ __launch_bounds__(TPB_BIN)
void binning_kernel(const int* __restrict__ erow, const int* __restrict__ ecol,
                    const float* __restrict__ evals,
                    int* __restrict__ gfill_r, int* __restrict__ gfill_c,
                    ull* __restrict__ br, unsigned int* __restrict__ bc,
                    int E, int NB, int chunk) {
    __shared__ int hr[8][MAXNB];
    __shared__ int hc[8][MAXNB];
    __shared__ int fr[MAXNB];
    __shared__ int fc[MAXNB];
    int t = threadIdx.x;
    int wv = t >> 6;
    for (int k = t; k < 8 * MAXNB; k += TPB_BIN) { (&hr[0][0])[k] = 0; (&hc[0][0])[k] = 0; }
    __syncthreads();
    int lo = blockIdx.x * chunk;             // chunk multiple of 4 -> lo 16B-aligned
    int hi = min(E, lo + chunk);
    int nq = (hi - lo) >> 2;
    int rem = (hi - lo) & 3;
    for (int p = t; p < nq; p += TPB_BIN) {
        int i = lo + 4 * p;
        int4 r4 = *(const int4*)(erow + i);
        int4 c4 = *(const int4*)(ecol + i);
        atomicAdd(&hr[wv][r4.x >> 10], 1);
        atomicAdd(&hr[wv][r4.y >> 10], 1);
        atomicAdd(&hr[wv][r4.z >> 10], 1);
        atomicAdd(&hr[wv][r4.w >> 10], 1);
        atomicAdd(&hc[wv][c4.x >> 10], 1);
        atomicAdd(&hc[wv][c4.y >> 10], 1);
        atomicAdd(&hc[wv][c4.z >> 10], 1);
        atomicAdd(&hc[wv][c4.w >> 10], 1);
    }
    if (t == 0) {
        for (int i = hi - rem; i < hi; i++) {
            atomicAdd(&hr[0][erow[i] >> 10], 1);
            atomicAdd(&hc[0][ecol[i] >> 10], 1);
        }
    }
    __syncthreads();
    if (t < NB) {
        int sr = 0, sc = 0;
        #pragma unroll
        for (int w2 = 0; w2 < 8; w2++) { sr += hr[w2][t]; sc += hc[w2][t]; }
        fr[t] = atomicAdd(&gfill_r[t * 16], sr);
        fc[t] = atomicAdd(&gfill_c[t * 16], sc);
    }
    __syncthreads();
    for (int p = t; p < nq; p += TPB_BIN) {
        int i = lo + 4 * p;
        int4 r4 = *(const int4*)(erow + i);
        int4 c4 = *(const int4*)(ecol + i);
        float4 v4 = *(const float4*)(evals + i);
        int pos0 = atomicAdd(&fr[r4.x >> 10], 1);
        int pos1 = atomicAdd(&fr[r4.y >> 10], 1);
        int pos2 = atomicAdd(&fr[r4.z >> 10], 1);
        int pos3 = atomicAdd(&fr[r4.w >> 10], 1);
        br[pos0] = ((ull)__float_as_uint(v4.x) << 32) | ((ull)(r4.x & 1023) << LRSHIFT) | (unsigned)c4.x;
        br[pos1] = ((ull)__float_as_uint(v4.y) << 32) | ((ull)(r4.y & 1023) << LRSHIFT) | (unsigned)c4.y;
        br[pos2] = ((ull)__float_as_uint(v4.z) << 32) | ((ull)(r4.z & 1023) << LRSHIFT) | (unsigned)c4.z;
        br[pos3] = ((ull)__float_as_uint(v4.w) << 32) | ((ull)(r4.w & 1023) << LRSHIFT) | (unsigned)c4.w;
        int q0 = atomicAdd(&fc[c4.x >> 10], 1);
        int q1 = atomicAdd(&fc[c4.y >> 10], 1);
        int q2 = atomicAdd(&fc[c4.z >> 10], 1);
        int q3 = atomicAdd(&fc[c4.w >> 10], 1);
        bc[q0] = bf16_hi(v4.x) | (unsigned)(c4.x & 1023);
        bc[q1] = bf16_hi(v4.y) | (unsigned)(c4.y & 1023);
        bc[q2] = bf16_hi(v4.z) | (unsigned)(c4.z & 1023);
        bc[q3] = bf16_hi(v4.w) | (unsigned)(c4.w & 1023);
    }
    if (t == 0) {
        for (int i = hi - rem; i < hi; i++) {
            int r = erow[i], c = ecol[i];
            float v = evals[i];
            int pos = atomicAdd(&fr[r >> 10], 1);
            br[pos] = ((ull)__float_as_uint(v) << 32) | ((ull)(r & 1023) << LRSHIFT) | (unsigned)c;
            int pos2 = atomicAdd(&fc[c >> 10], 1);
            bc[pos2] = bf16_hi(v) | (unsigned)(c & 1023);
        }
    }
}

// ---- count: block (bucket b, chunk ch) reads its 1/8 edge slice ONCE, 2-edge ILP ----
__global__ __launch_bounds__(TPB_CP)
void count_kernel(const ull* __restrict__ br, const unsigned int* __restrict__ bc,
                  const int* __restrict__ gfill_r, const int* __restrict__ gfill_c,
                  int* __restrict__ subcnt, float* __restrict__ subds,
                  float* __restrict__ subdsc, int cap) {
    __shared__ int cnt[BUCKET];
    __shared__ float ds[BUCKET];
    __shared__ float dsc[BUCKET];
    int b = blockIdx.x >> 3, ch = blockIdx.x & 7;
    int t = threadIdx.x;
    for (int k = t; k < BUCKET; k += TPB_CP) { cnt[k] = 0; ds[k] = 0.0f; dsc[k] = 0.0f; }
    __syncthreads();
    int s = b * cap;                              // cap mult of 64 -> s even
    int e = gfill_r[b * 16];
    int len = ((((e - s) + 7) >> 3) + 1) & ~1;    // even slice length
    int cs = s + ch * len, ce = min(e, cs + len);
    int m = cs + ((ce - cs) & ~1);
    for (int i = cs + 2 * t; i < m; i += 2 * TPB_CP) {
        ull p0 = br[i];
        ull p1 = br[i + 1];
        int lr0 = (int)((p0 >> LRSHIFT) & LRMASK);
        int lr1 = (int)((p1 >> LRSHIFT) & LRMASK);
        atomicAdd(&cnt[lr0], 1);
        atomicAdd(&cnt[lr1], 1);
        atomicAdd(&ds[lr0], __uint_as_float((unsigned)(p0 >> 32)));
        atomicAdd(&ds[lr1], __uint_as_float((unsigned)(p1 >> 32)));
    }
    if (t == 0 && m < ce) {
        ull p = br[m];
        int lr = (int)((p >> LRSHIFT) & LRMASK);
        atomicAdd(&cnt[lr], 1);
        atomicAdd(&ds[lr], __uint_as_float((unsigned)(p >> 32)));
    }
    int e2 = gfill_c[b * 16];
    int len2 = ((((e2 - s) + 7) >> 3) + 1) & ~1;
    int cs2 = s + ch * len2, ce2 = min(e2, cs2 + len2);
    int m2 = cs2 + ((ce2 - cs2) & ~1);
    for (int i = cs2 + 2 * t; i < m2; i += 2 * TPB_CP) {
        uint2 p = *(const uint2*)(bc + i);
        atomicAdd(&dsc[p.x & 0x3FFu], __uint_as_float(p.x & 0xffff0000u));
        atomicAdd(&dsc[p.y & 0x3FFu], __uint_as_float(p.y & 0xffff0000u));
    }
    if (t == 0 && m2 < ce2) {
        unsigned int p = bc[m2];
        atomicAdd(&dsc[p & 0x3FFu], __uint_as_float(p & 0xffff0000u));
    }
    __syncthreads();
    size_t base = ((size_t)b * 8 + ch) * BUCKET;
    for (int k = t; k < BUCKET; k += TPB_CP) {
        subcnt[base + k] = cnt[k];
        subds[base + k]  = ds[k];
        subdsc[base + k] = dsc[k];
    }
}

// ---- combine: even-rounded scan -> even rowstart, per-chunk bases, inv_r, inv_c ----
__global__ __launch_bounds__(1024)
void combine_kernel(int* __restrict__ subcnt, const float* __restrict__ subds,
                    const float* __restrict__ subdsc,
                    int* __restrict__ rowstart, int* __restrict__ rowend,
                    float* __restrict__ inv_r, float* __restrict__ inv_c,
                    int N, int cap) {
    __shared__ int tot[BUCKET];
    int b = blockIdx.x, t = threadIdx.x;
    size_t base = (size_t)b * 8 * BUCKET;
    int c8[8];
    int sum = 0;
    #pragma unroll
    for (int c = 0; c < 8; c++) { c8[c] = subcnt[base + c * BUCKET + t]; sum += c8[c]; }
    int sum2 = (sum + 1) & ~1;           // even-rounded slot count -> even row starts
    tot[t] = sum2;
    __syncthreads();
    for (int off = 1; off < BUCKET; off <<= 1) {
        int v = (t >= off) ? tot[t - off] : 0;
        __syncthreads();
        tot[t] += v;
        __syncthreads();
    }
    int excl = tot[t] - sum2;
    int node = b * BUCKET + t;
    int s = b * cap;
    if (node < N) {
        rowstart[node] = s + excl;
        rowend[node]   = s + excl + sum;
    }
    int run = s + excl;
    #pragma unroll
    for (int c = 0; c < 8; c++) { int v = c8[c]; subcnt[base + c * BUCKET + t] = run; run += v; }
    float d = 0.0f, dc = 0.0f;
    #pragma unroll
    for (int c = 0; c < 8; c++) { d += subds[base + c * BUCKET + t]; dc += subdsc[base + c * BUCKET + t]; }
    inv_r[b * BUCKET + t] = 1.0f / (sqrtf(d) + 1e-8f);
    inv_c[b * BUCKET + t] = 1.0f / (sqrtf(dc) + 1e-8f);
}

// ---- place: ranked placement, 2-edge ILP; 4 B entry = col<<15 | f16w>>1 ----
__global__ __launch_bounds__(TPB_CP)
void place_kernel(const ull* __restrict__ br, const int* __restrict__ gfill_r,
                  const int* __restrict__ pbase, const float* __restrict__ inv_r,
                  const float* __restrict__ inv_c,
                  unsigned int* __restrict__ cw, int cap) {
    __shared__ int fill[BUCKET];
    __shared__ float irs[BUCKET];
    int b = blockIdx.x >> 3, ch = blockIdx.x & 7;
    int t = threadIdx.x;
    size_t pb = ((size_t)b * 8 + ch) * BUCKET;
    for (int k = t; k < BUCKET; k += TPB_CP) {
        fill[k] = pbase[pb + k];
        irs[k]  = inv_r[b * BUCKET + k];
    }
    __syncthreads();
    int s = b * cap;
    int e = gfill_r[b * 16];
    int len = ((((e - s) + 7) >> 3) + 1) & ~1;
    int cs = s + ch * len, ce = min(e, cs + len);
    int m = cs + ((ce - cs) & ~1);
    for (int i = cs + 2 * t; i < m; i += 2 * TPB_CP) {
        ull p0 = br[i];
        ull p1 = br[i + 1];
        int c0 = (int)(p0 & CMASK), c1 = (int)(p1 & CMASK);
        int lr0 = (int)((p0 >> LRSHIFT) & LRMASK);
        int lr1 = (int)((p1 >> LRSHIFT) & LRMASK);
        float v0 = __uint_as_float((unsigned)(p0 >> 32));
        float v1 = __uint_as_float((unsigned)(p1 >> 32));
        int pos0 = atomicAdd(&fill[lr0], 1);
        int pos1 = atomicAdd(&fill[lr1], 1);
        float w0 = v0 * inv_c[c0] * irs[lr0];
        float w1 = v1 * inv_c[c1] * irs[lr1];
        cw[pos0] = ((unsigned)c0 << 15) | ((pk_f16x2(w0, w0) & 0xFFFFu) >> 1);
        cw[pos1] = ((unsigned)c1 << 15) | ((pk_f16x2(w1, w1) & 0xFFFFu) >> 1);
    }
    if (t == 0 && m < ce) {
        ull p = br[m];
        int c = (int)(p & CMASK);
        int lr = (int)((p >> LRSHIFT) & LRMASK);
        float v = __uint_as_float((unsigned)(p >> 32));
        int pos = atomicAdd(&fill[lr], 1);
        float wv = v * inv_c[c] * irs[lr];
        cw[pos] = ((unsigned)c << 15) | ((pk_f16x2(wv, wv) & 0xFFFFu) >> 1);
    }
}

// ---- fused: acc16 = f16(nf), fb0 = f16(nf); 4 floats/thread ----
__global__ void cvt_kernel(const float* __restrict__ src, unsigned int* __restrict__ acc16,
                           unsigned int* __restrict__ dst, long n4) {
    long i = (long)blockIdx.x * blockDim.x + threadIdx.x;
    if (i < n4) {
        float4 v = ((const float4*)src)[i];
        uint2 o;
        o.x = pk_f16x2(v.x, v.y);
        o.y = pk_f16x2(v.z, v.w);
        ((uint2*)acc16)[i] = o;
        ((uint2*)dst)[i] = o;
    }
}

// ---- SpMM: wave per row, edge pairs via uint2 cw load, v_pk_fma_f16, f16 acc ----
__global__ __launch_bounds__(256)
void spmm_f16_kernel(const int* __restrict__ rowstart, const int* __restrict__ rowend,
                     const unsigned int* __restrict__ cw,
                     const unsigned short* __restrict__ fin,
                     unsigned short* __restrict__ fout,
                     unsigned short* __restrict__ acc16, int N, int writeOut) {
    int wid = blockIdx.x * (blockDim.x >> 6) + (threadIdx.x >> 6);   // row
    if (wid >= N) return;
    int lane = threadIdx.x & 63;
    int g = lane >> 3;          // edge-pair slot 0..7 (16 edges per iteration)
    int h = lane & 7;           // feature chunk (8 f16 = 16 B)
    int s = rowstart[wid], e = rowend[wid];   // s even -> uint2-aligned cw pairs
    half2_t a2[8];
    #pragma unroll
    for (int k = 0; k < 8; k++) a2[k] = (half2_t)0;

    int nfull = (e - s) >> 4;
    int base = s;
    for (int it = 0; it < nfull; it++, base += 16) {
        int j0 = base + 2 * g;
        uint2 pw = *(const uint2*)(cw + j0);
        int c0 = (int)(pw.x >> 15);
        int c1 = (int)(pw.y >> 15);
        uint4 q0 = ((const uint4*)(fin + ((long)c0 << 6)))[h];
        uint4 q1 = ((const uint4*)(fin + ((long)c1 << 6)))[h];
        half2_t w0 = dup_lo16(pw.x << 1);
        half2_t w1 = dup_lo16(pw.y << 1);
        a2[0] += w0 * __builtin_bit_cast(half2_t, q0.x);
        a2[1] += w0 * __builtin_bit_cast(half2_t, q0.y);
        a2[2] += w0 * __builtin_bit_cast(half2_t, q0.z);
        a2[3] += w0 * __builtin_bit_cast(half2_t, q0.w);
        a2[4] += w1 * __builtin_bit_cast(half2_t, q1.x);
        a2[5] += w1 * __builtin_bit_cast(half2_t, q1.y);
        a2[6] += w1 * __builtin_bit_cast(half2_t, q1.z);
        a2[7] += w1 * __builtin_bit_cast(half2_t, q1.w);
    }
    if (base < e) {
        int j0 = base + 2 * g, j1 = j0 + 1;
        uint2 pw = *(const uint2*)(cw + j0);   // in padded region; poison col < 2^17
        int c0 = (int)(pw.x >> 15);
        int c1 = (int)(pw.y >> 15);
        half2_t w0 = (j0 < e) ? dup_lo16(pw.x << 1) : (half2_t)0;
        half2_t w1 = (j1 < e) ? dup_lo16(pw.y << 1) : (half2_t)0;
        uint4 q0 = ((const uint4*)(fin + ((long)c0 << 6)))[h];
        uint4 q1 = ((const uint4*)(fin + ((long)c1 << 6)))[h];
        a2[0] += w0 * __builtin_bit_cast(half2_t, q0.x);
        a2[1] += w0 * __builtin_bit_cast(half2_t, q0.y);
        a2[2] += w0 * __builtin_bit_cast(half2_t, q0.z);
        a2[3] += w0 * __builtin_bit_cast(half2_t, q0.w);
        a2[4] += w1 * __builtin_bit_cast(half2_t, q1.x);
        a2[5] += w1 * __builtin_bit_cast(half2_t, q1.y);
        a2[6] += w1 * __builtin_bit_cast(half2_t, q1.z);
        a2[7] += w1 * __builtin_bit_cast(half2_t, q1.w);
    }

    float a[8];
    #pragma unroll
    for (int k = 0; k < 4; k++) {
        a[2 * k]     = (float)a2[k][0] + (float)a2[k + 4][0];
        a[2 * k + 1] = (float)a2[k][1] + (float)a2[k + 4][1];
    }
    #pragma unroll
    for (int k = 0; k < 8; k++) {
        a[k] += __shfl_xor(a[k], 8);
        a[k] += __shfl_xor(a[k], 16);
        a[k] += __shfl_xor(a[k], 32);
    }
    float ss = 0.0f;
    #pragma unroll
    for (int k = 0; k < 8; k++) ss += a[k] * a[k];
    ss += __shfl_xor(ss, 1);
    ss += __shfl_xor(ss, 2);
    ss += __shfl_xor(ss, 4);
    float s2 = 1.0f / fmaxf(sqrtf(ss), 1e-12f);
    if (g == 0) {
        uint4 o;
        o.x = pk_f16x2(a[0], a[1]);
        o.y = pk_f16x2(a[2], a[3]);
        o.z = pk_f16x2(a[4], a[5]);
        o.w = pk_f16x2(a[6], a[7]);
        if (writeOut) ((uint4*)(fout + ((long)wid << 6)))[h] = o;
        uint4* ap = (uint4*)(acc16 + ((long)wid << 6)) + h;
        uint4 old = *ap;
        uint4 inc;
        inc.x = pk_f16x2(a[0] * s2, a[1] * s2);
        inc.y = pk_f16x2(a[2] * s2, a[3] * s2);
        inc.z = pk_f16x2(a[4] * s2, a[5] * s2);
        inc.w = pk_f16x2(a[6] * s2, a[7] * s2);
        uint4 nw;
        nw.x = __builtin_bit_cast(unsigned int, __builtin_bit_cast(half2_t, old.x) + __builtin_bit_cast(half2_t, inc.x));
        nw.y = __builtin_bit_cast(unsigned int, __builtin_bit_cast(half2_t, old.y) + __builtin_bit_cast(half2_t, inc.y));
        nw.z = __builtin_bit_cast(unsigned int, __builtin_bit_cast(half2_t, old.z) + __builtin_bit_cast(half2_t, inc.z));
        nw.w = __builtin_bit_cast(unsigned int, __builtin_bit_cast(half2_t, old.w) + __builtin_bit_cast(half2_t, inc.w));
        *ap = nw;
    }
}

// ---- BPR loss (acc in f16) ----
__global__ void loss_terms_kernel(const unsigned short* __restrict__ acc16,
                                  const int* __restrict__ a_id, const int* __restrict__ p_id,
                                  const int* __restrict__ n_id,
                                  float* __restrict__ terms, int B) {
    long gid = (long)blockIdx.x * blockDim.x + threadIdx.x;
    int b = (int)(gid >> 6);
    int lane = threadIdx.x & 63;
    if (b < B) {
        int ia = a_id[b], ip = p_id[b], in2 = n_id[b];
        float a = (float)__builtin_bit_cast(_Float16, acc16[(long)ia * DDIM + lane]);
        float p = (float)__builtin_bit_cast(_Float16, acc16[(long)ip * DDIM + lane]);
        float n = (float)__builtin_bit_cast(_Float16, acc16[(long)in2 * DDIM + lane]);
        float dp = a * p, dn = a * n;
        #pragma unroll
        for (int off = 1; off < 64; off <<= 1) { dp += __shfl_xor(dp, off); dn += __shfl_xor(dn, off); }
        if (lane == 0) {
            float x = (dp - dn) * 0.0625f;   // node_rep = acc/4 -> preds scale 1/16
            terms[b] = fmaxf(-x, 0.0f) + log1pf(expf(-fabsf(x)));
        }
    }
}

__global__ void reduce_kernel(const float* __restrict__ terms, float* __restrict__ out, int B) {
    __shared__ float sm[256];
    float s = 0.0f;
    for (int i = threadIdx.x; i < B; i += 256) s += terms[i];
    sm[threadIdx.x] = s;
    __syncthreads();
    for (int stride = 128; stride > 0; stride >>= 1) {
        if (threadIdx.x < stride) sm[threadIdx.x] += sm[threadIdx.x + stride];
        __syncthreads();
    }
    if (threadIdx.x == 0) out[0] = sm[0] / (float)B;
}

extern "C" void kernel_launch(void* const* d_in, const int* in_sizes, int n_in,
                              void* d_out, int out_size, void* d_ws, size_t ws_size,
                              hipStream_t stream) {
    const float* nf    = (const float*)d_in[0];
    const int*   erow  = (const int*)d_in[1];
    const int*   ecol  = (const int*)d_in[2];
    const float* evals = (const float*)d_in[3];
    const int*   a_id  = (const int*)d_in[4];
    const int*   p_id  = (const int*)d_in[5];
    const int*   n_id  = (const int*)d_in[6];

    int N = in_sizes[0] / DDIM;
    int E = in_sizes[1];
    int B = in_sizes[4];
    int NB = (N + BUCKET - 1) / BUCKET;
    int chunk = (((E + NBLK - 1) / NBLK) + 3) & ~3;   // multiple of 4 -> aligned quad loads
    int Npad = NB * BUCKET;

    // bucket capacity: mean + ~8.3% + 2048 (even-rounding pad + >10 sigma)
    long capl = ((long)E * BUCKET) / N;
    int cap = (int)(capl + capl / 12 + 2048);
    cap = (cap + 63) & ~63;

    size_t regionA = (size_t)cap * NB * 8;            // br (8 B), later fb0+fb1
    size_t regionB = (size_t)cap * NB * 4;            // bc (4 B), later cw (4 B)
    size_t featB16 = (size_t)N * DDIM * 2;
    size_t subBytes = (size_t)NB * 8 * BUCKET * 4;

    char* w = (char*)d_ws;
    ull*  br     = (ull*)w;
    char* regAp  = w;                 w += regionA;
    unsigned int* bc = (unsigned int*)w;
    unsigned int* cw = (unsigned int*)w;  w += regionB + 64;   // +64: spmm tail overread pad
    unsigned int* acc16 = (unsigned int*)w;  w += featB16;
    int* subcnt  = (int*)w;           w += subBytes;    // becomes pbase in combine
    float* subds = (float*)w;         w += subBytes;
    float* subdsc= (float*)w;         w += subBytes;
    float* inv_c = (float*)w;         w += (size_t)Npad * 4;
    float* inv_r = (float*)w;         w += (size_t)Npad * 4;
    int* rowstart= (int*)w;           w += (size_t)N * 4;
    int* rowend  = (int*)w;           w += (size_t)N * 4;
    int* gfill_r = (int*)w;           w += (size_t)NB * 16 * 4;
    int* gfill_c = (int*)w;           w += (size_t)NB * 16 * 4;
    float* terms = (float*)w;         w += (size_t)B * 4;

    unsigned short* fb0 = (unsigned short*)regAp;             // aliases br (dead after place)
    unsigned short* fb1 = (unsigned short*)(regAp + featB16);

    init_fill_kernel<<<1, 128, 0, stream>>>(gfill_r, gfill_c, NB, cap);
    binning_kernel<<<NBLK, TPB_BIN, 0, stream>>>(erow, ecol, evals, gfill_r, gfill_c,
                                                 br, bc, E, NB, chunk);
    count_kernel<<<NB * 8, TPB_CP, 0, stream>>>(br, bc, gfill_r, gfill_c,
                                                subcnt, subds, subdsc, cap);
    combine_kernel<<<NB, 1024, 0, stream>>>(subcnt, subds, subdsc, rowstart, rowend,
                                            inv_r, inv_c, N, cap);
    place_kernel<<<NB * 8, TPB_CP, 0, stream>>>(br, gfill_r, subcnt, inv_r, inv_c, cw, cap);

    long n4 = (long)N * DDIM / 4;
    cvt_kernel<<<(unsigned)((n4 + 255) / 256), 256, 0, stream>>>(nf, acc16, (unsigned int*)fb0, n4);

    unsigned spmmGrid = (unsigned)((N + 3) / 4);   // 4 waves (rows) per 256-thread block
    spmm_f16_kernel<<<spmmGrid, 256, 0, stream>>>(rowstart, rowend, cw, fb0, fb1,
                                                  (unsigned short*)acc16, N, 1);
    spmm_f16_kernel<<<spmmGrid, 256, 0, stream>>>(rowstart, rowend, cw, fb1, fb0,
                                                  (unsigned short*)acc16, N, 1);
    spmm_f16_kernel<<<spmmGrid, 256, 0, stream>>>(rowstart, rowend, cw, fb0, fb1,
                                                  (unsigned short*)acc16, N, 0);

    loss_terms_kernel<<<(unsigned)(((long)B * 64 + 255) / 256), 256, 0, stream>>>(
        (const unsigned short*)acc16, a_id, p_id, n_id, terms, B);
    reduce_kernel<<<1, 256, 0, stream>>>(terms, (float*)d_out, B);
}

// Round 15
// 424.419 us; speedup vs baseline: 1.0806x; 1.0015x over previous
//
#include <hip/hip_runtime.h>
#include <math.h>

#define DDIM 64
#define BUCKET 1024             // nodes per binning bucket
#define CMASK 0x1FFFF
#define NBLK 512
#define TPB_BIN 1024
#define NWV 16                  // waves per binning block
#define TPB_CP 512
#define MAXNB 128               // max buckets (NB = ceil(100000/1024) = 98)

typedef unsigned long long ull;
typedef _Float16 half2_t __attribute__((ext_vector_type(2)));

__device__ inline unsigned short bf16_of(float v) {     // RNE bf16 bits
    unsigned int a = __float_as_uint(v);
    return (unsigned short)((a + 0x7fffu + ((a >> 16) & 1u)) >> 16);
}

__device__ inline unsigned int bf16_hi(float v) {       // RNE bf16 bits in high 16
    unsigned int a = __float_as_uint(v);
    return (a + 0x7fffu + ((a >> 16) & 1u)) & 0xffff0000u;
}

__device__ inline float bf16_to_f(unsigned int bits16) {
    return __uint_as_float(bits16 << 16);
}

__device__ inline unsigned int pk_f16x2(float lo, float hi) {
    return __builtin_bit_cast(unsigned int, __builtin_amdgcn_cvt_pkrtz(lo, hi));
}

__device__ inline half2_t dup_lo16(unsigned int s) {    // (s&0xFFFF) in both halves
    return __builtin_bit_cast(half2_t, __builtin_amdgcn_perm(0u, s, 0x01000100u));
}

// ---- init global fill counters (cacheline-padded: stride 16 ints) ----
__global__ void init_fill_kernel(int* __restrict__ gfill_r, int* __restrict__ gfill_c,
                                 int NB, int cap) {
    int k = blockIdx.x * blockDim.x + threadIdx.x;
    if (k < NB) {
        gfill_r[k * 16] = k * cap;
        gfill_c[k * 16] = k * cap;
    }
}

// ---- fused binning: 16 per-wave histograms, BLOCK-level reserve + place, 4-edge ILP ----
__global__ __launch_bounds__(TPB_BIN)
void binning_kernel(const int* __restrict__ erow, const int* __restrict__ ecol,
                    const float* __restrict__ evals,
                    int* __restrict__ gfill_r, int* __restrict__ gfill_c,
                    unsigned int* __restrict__ brk, unsigned short* __restrict__ brv,
                    unsigned int* __restrict__ bc,
                    int E, int NB, int chunk) {
    __shared__ int hr[NWV][MAXNB];
    __shared__ int hc[NWV][MAXNB];
    __shared__ int fr[MAXNB];
    __shared__ int fc[MAXNB];
    int t = threadIdx.x;
    int wv = t >> 6;
    for (int k = t; k < NWV * MAXNB; k += TPB_BIN) { (&hr[0][0])[k] = 0; (&hc[0][0])[k] = 0; }
    __syncthreads();
    int lo = blockIdx.x * chunk;             // chunk multiple of 4 -> lo 16B-aligned
    int hi = min(E, lo + chunk);
    int nq = (hi - lo) >> 2;
    int rem = (hi - lo) & 3;
    // phase 1: per-wave count, 4 edges per thread
    for (int p = t; p < nq; p += TPB_BIN) {
        int i = lo + 4 * p;
        int4 r4 = *(const int4*)(erow + i);
        int4 c4 = *(const int4*)(ecol + i);
        atomicAdd(&hr[wv][r4.x >> 10], 1);
        atomicAdd(&hr[wv][r4.y >> 10], 1);
        atomicAdd(&hr[wv][r4.z >> 10], 1);
        atomicAdd(&hr[wv][r4.w >> 10], 1);
        atomicAdd(&hc[wv][c4.x >> 10], 1);
        atomicAdd(&hc[wv][c4.y >> 10], 1);
        atomicAdd(&hc[wv][c4.z >> 10], 1);
        atomicAdd(&hc[wv][c4.w >> 10], 1);
    }
    if (t == 0) {
        for (int i = hi - rem; i < hi; i++) {
            atomicAdd(&hr[0][erow[i] >> 10], 1);
            atomicAdd(&hc[0][ecol[i] >> 10], 1);
        }
    }
    __syncthreads();
    // phase 2: ONE reservation per (block,bucket); per-wave bases
    if (t < NB) {
        int sr = 0, sc = 0;
        #pragma unroll
        for (int w2 = 0; w2 < NWV; w2++) { sr += hr[w2][t]; sc += hc[w2][t]; }
        int basr = atomicAdd(&gfill_r[t * 16], sr);
        int basc = atomicAdd(&gfill_c[t * 16], sc);
        fr[t] = basr; fc[t] = basc;
        #pragma unroll
        for (int w2 = 0; w2 < NWV; w2++) {
            int a = hr[w2][t]; hr[w2][t] = basr; basr += a;
            int b = hc[w2][t]; hc[w2][t] = basc; basc += b;
        }
    }
    __syncthreads();
    // phase 3: place 4 edges per thread into per-wave sub-runs (block-contiguous)
    for (int p = t; p < nq; p += TPB_BIN) {
        int i = lo + 4 * p;
        int4 r4 = *(const int4*)(erow + i);
        int4 c4 = *(const int4*)(ecol + i);
        float4 v4 = *(const float4*)(evals + i);
        int pos0 = atomicAdd(&hr[wv][r4.x >> 10], 1);
        int pos1 = atomicAdd(&hr[wv][r4.y >> 10], 1);
        int pos2 = atomicAdd(&hr[wv][r4.z >> 10], 1);
        int pos3 = atomicAdd(&hr[wv][r4.w >> 10], 1);
        brk[pos0] = ((unsigned)(r4.x & 1023) << 17) | (unsigned)c4.x;
        brk[pos1] = ((unsigned)(r4.y & 1023) << 17) | (unsigned)c4.y;
        brk[pos2] = ((unsigned)(r4.z & 1023) << 17) | (unsigned)c4.z;
        brk[pos3] = ((unsigned)(r4.w & 1023) << 17) | (unsigned)c4.w;
        brv[pos0] = bf16_of(v4.x);
        brv[pos1] = bf16_of(v4.y);
        brv[pos2] = bf16_of(v4.z);
        brv[pos3] = bf16_of(v4.w);
        int q0 = atomicAdd(&hc[wv][c4.x >> 10], 1);
        int q1 = atomicAdd(&hc[wv][c4.y >> 10], 1);
        int q2 = atomicAdd(&hc[wv][c4.z >> 10], 1);
        int q3 = atomicAdd(&hc[wv][c4.w >> 10], 1);
        bc[q0] = bf16_hi(v4.x) | (unsigned)(c4.x & 1023);
        bc[q1] = bf16_hi(v4.y) | (unsigned)(c4.y & 1023);
        bc[q2] = bf16_hi(v4.z) | (unsigned)(c4.z & 1023);
        bc[q3] = bf16_hi(v4.w) | (unsigned)(c4.w & 1023);
    }
    if (t == 0) {
        for (int i = hi - rem; i < hi; i++) {
            int r = erow[i], c = ecol[i];
            float v = evals[i];
            int pos = atomicAdd(&hr[0][r >> 10], 1);
            brk[pos] = ((unsigned)(r & 1023) << 17) | (unsigned)c;
            brv[pos] = bf16_of(v);
            int pos2 = atomicAdd(&hc[0][c >> 10], 1);
            bc[pos2] = bf16_hi(v) | (unsigned)(c & 1023);
        }
    }
}

// ---- count: block (bucket b, chunk ch) reads its 1/8 edge slice ONCE, 2-edge ILP ----
__global__ __launch_bounds__(TPB_CP)
void count_kernel(const unsigned int* __restrict__ brk, const unsigned short* __restrict__ brv,
                  const unsigned int* __restrict__ bc,
                  const int* __restrict__ gfill_r, const int* __restrict__ gfill_c,
                  int* __restrict__ subcnt, float* __restrict__ subds,
                  float* __restrict__ subdsc, int cap) {
    __shared__ int cnt[BUCKET];
    __shared__ float ds[BUCKET];
    __shared__ float dsc[BUCKET];
    int b = blockIdx.x >> 3, ch = blockIdx.x & 7;
    int t = threadIdx.x;
    for (int k = t; k < BUCKET; k += TPB_CP) { cnt[k] = 0; ds[k] = 0.0f; dsc[k] = 0.0f; }
    __syncthreads();
    int s = b * cap;                              // cap mult of 64 -> s even
    int e = gfill_r[b * 16];
    int len = ((((e - s) + 7) >> 3) + 1) & ~1;    // even slice length
    int cs = s + ch * len, ce = min(e, cs + len);
    int m = cs + ((ce - cs) & ~1);
    for (int i = cs + 2 * t; i < m; i += 2 * TPB_CP) {
        uint2 k2 = *(const uint2*)(brk + i);
        unsigned int v2 = *(const unsigned int*)(brv + i);   // i even -> 4B aligned
        int lr0 = (int)(k2.x >> 17);
        int lr1 = (int)(k2.y >> 17);
        atomicAdd(&cnt[lr0], 1);
        atomicAdd(&cnt[lr1], 1);
        atomicAdd(&ds[lr0], bf16_to_f(v2 & 0xFFFFu));
        atomicAdd(&ds[lr1], bf16_to_f(v2 >> 16));
    }
    if (t == 0 && m < ce) {
        unsigned int k = brk[m];
        int lr = (int)(k >> 17);
        atomicAdd(&cnt[lr], 1);
        atomicAdd(&ds[lr], bf16_to_f((unsigned int)brv[m]));
    }
    int e2 = gfill_c[b * 16];
    int len2 = ((((e2 - s) + 7) >> 3) + 1) & ~1;
    int cs2 = s + ch * len2, ce2 = min(e2, cs2 + len2);
    int m2 = cs2 + ((ce2 - cs2) & ~1);
    for (int i = cs2 + 2 * t; i < m2; i += 2 * TPB_CP) {
        uint2 p = *(const uint2*)(bc + i);
        atomicAdd(&dsc[p.x & 0x3FFu], __uint_as_float(p.x & 0xffff0000u));
        atomicAdd(&dsc[p.y & 0x3FFu], __uint_as_float(p.y & 0xffff0000u));
    }
    if (t == 0 && m2 < ce2) {
        unsigned int p = bc[m2];
        atomicAdd(&dsc[p & 0x3FFu], __uint_as_float(p & 0xffff0000u));
    }
    __syncthreads();
    size_t base = ((size_t)b * 8 + ch) * BUCKET;
    for (int k = t; k < BUCKET; k += TPB_CP) {
        subcnt[base + k] = cnt[k];
        subds[base + k]  = ds[k];
        subdsc[base + k] = dsc[k];
    }
}

// ---- combine: even-rounded scan -> even rowstart, per-chunk bases, inv_r, inv_c ----
__global__ __launch_bounds__(1024)
void combine_kernel(int* __restrict__ subcnt, const float* __restrict__ subds,
                    const float* __restrict__ subdsc,
                    int* __restrict__ rowstart, int* __restrict__ rowend,
                    float* __restrict__ inv_r, float* __restrict__ inv_c,
                    int N, int cap) {
    __shared__ int tot[BUCKET];
    int b = blockIdx.x, t = threadIdx.x;
    size_t base = (size_t)b * 8 * BUCKET;
    int c8[8];
    int sum = 0;
    #pragma unroll
    for (int c = 0; c < 8; c++) { c8[c] = subcnt[base + c * BUCKET + t]; sum += c8[c]; }
    int sum2 = (sum + 1) & ~1;           // even-rounded slot count -> even row starts
    tot[t] = sum2;
    __syncthreads();
    for (int off = 1; off < BUCKET; off <<= 1) {
        int v = (t >= off) ? tot[t - off] : 0;
        __syncthreads();
        tot[t] += v;
        __syncthreads();
    }
    int excl = tot[t] - sum2;
    int node = b * BUCKET + t;
    int s = b * cap;
    if (node < N) {
        rowstart[node] = s + excl;
        rowend[node]   = s + excl + sum;
    }
    int run = s + excl;
    #pragma unroll
    for (int c = 0; c < 8; c++) { int v = c8[c]; subcnt[base + c * BUCKET + t] = run; run += v; }
    float d = 0.0f, dc = 0.0f;
    #pragma unroll
    for (int c = 0; c < 8; c++) { d += subds[base + c * BUCKET + t]; dc += subdsc[base + c * BUCKET + t]; }
    inv_r[b * BUCKET + t] = 1.0f / (sqrtf(d) + 1e-8f);
    inv_c[b * BUCKET + t] = 1.0f / (sqrtf(dc) + 1e-8f);
}

// ---- place: ranked placement, 2-edge ILP; 4 B entry = col<<15 | f16w>>1 ----
__global__ __launch_bounds__(TPB_CP)
void place_kernel(const unsigned int* __restrict__ brk, const unsigned short* __restrict__ brv,
                  const int* __restrict__ gfill_r,
                  const int* __restrict__ pbase, const float* __restrict__ inv_r,
                  const float* __restrict__ inv_c,
                  unsigned int* __restrict__ cw, int cap) {
    __shared__ int fill[BUCKET];
    __shared__ float irs[BUCKET];
    int b = blockIdx.x >> 3, ch = blockIdx.x & 7;
    int t = threadIdx.x;
    size_t pb = ((size_t)b * 8 + ch) * BUCKET;
    for (int k = t; k < BUCKET; k += TPB_CP) {
        fill[k] = pbase[pb + k];
        irs[k]  = inv_r[b * BUCKET + k];
    }
    __syncthreads();
    int s = b * cap;
    int e = gfill_r[b * 16];
    int len = ((((e - s) + 7) >> 3) + 1) & ~1;
    int cs = s + ch * len, ce = min(e, cs + len);
    int m = cs + ((ce - cs) & ~1);
    for (int i = cs + 2 * t; i < m; i += 2 * TPB_CP) {
        uint2 k2 = *(const uint2*)(brk + i);
        unsigned int v2 = *(const unsigned int*)(brv + i);
        int c0 = (int)(k2.x & CMASK), c1 = (int)(k2.y & CMASK);
        int lr0 = (int)(k2.x >> 17);
        int lr1 = (int)(k2.y >> 17);
        float v0 = bf16_to_f(v2 & 0xFFFFu);
        float v1 = bf16_to_f(v2 >> 16);
        int pos0 = atomicAdd(&fill[lr0], 1);
        int pos1 = atomicAdd(&fill[lr1], 1);
        float w0 = v0 * inv_c[c0] * irs[lr0];
        float w1 = v1 * inv_c[c1] * irs[lr1];
        cw[pos0] = ((unsigned)c0 << 15) | ((pk_f16x2(w0, w0) & 0xFFFFu) >> 1);
        cw[pos1] = ((unsigned)c1 << 15) | ((pk_f16x2(w1, w1) & 0xFFFFu) >> 1);
    }
    if (t == 0 && m < ce) {
        unsigned int k = brk[m];
        int c = (int)(k & CMASK);
        int lr = (int)(k >> 17);
        float v = bf16_to_f((unsigned int)brv[m]);
        int pos = atomicAdd(&fill[lr], 1);
        float wv = v * inv_c[c] * irs[lr];
        cw[pos] = ((unsigned)c << 15) | ((pk_f16x2(wv, wv) & 0xFFFFu) >> 1);
    }
}

// ---- fused: acc16 = f16(nf), fb0 = f16(nf); 4 floats/thread ----
__global__ void cvt_kernel(const float* __restrict__ src, unsigned int* __restrict__ acc16,
                           unsigned int* __restrict__ dst, long n4) {
    long i = (long)blockIdx.x * blockDim.x + threadIdx.x;
    if (i < n4) {
        float4 v = ((const float4*)src)[i];
        uint2 o;
        o.x = pk_f16x2(v.x, v.y);
        o.y = pk_f16x2(v.z, v.w);
        ((uint2*)acc16)[i] = o;
        ((uint2*)dst)[i] = o;
    }
}

// ---- SpMM: wave per row, edge pairs via uint2 cw load, v_pk_fma_f16, f16 acc ----
__global__ __launch_bounds__(256)
void spmm_f16_kernel(const int* __restrict__ rowstart, const int* __restrict__ rowend,
                     const unsigned int* __restrict__ cw,
                     const unsigned short* __restrict__ fin,
                     unsigned short* __restrict__ fout,
                     unsigned short* __restrict__ acc16, int N, int writeOut) {
    int wid = blockIdx.x * (blockDim.x >> 6) + (threadIdx.x >> 6);   // row
    if (wid >= N) return;
    int lane = threadIdx.x & 63;
    int g = lane >> 3;          // edge-pair slot 0..7 (16 edges per iteration)
    int h = lane & 7;           // feature chunk (8 f16 = 16 B)
    int s = rowstart[wid], e = rowend[wid];   // s even -> uint2-aligned cw pairs
    half2_t a2[8];
    #pragma unroll
    for (int k = 0; k < 8; k++) a2[k] = (half2_t)0;

    int nfull = (e - s) >> 4;
    int base = s;
    for (int it = 0; it < nfull; it++, base += 16) {
        int j0 = base + 2 * g;
        uint2 pw = *(const uint2*)(cw + j0);
        int c0 = (int)(pw.x >> 15);
        int c1 = (int)(pw.y >> 15);
        uint4 q0 = ((const uint4*)(fin + ((long)c0 << 6)))[h];
        uint4 q1 = ((const uint4*)(fin + ((long)c1 << 6)))[h];
        half2_t w0 = dup_lo16(pw.x << 1);
        half2_t w1 = dup_lo16(pw.y << 1);
        a2[0] += w0 * __builtin_bit_cast(half2_t, q0.x);
        a2[1] += w0 * __builtin_bit_cast(half2_t, q0.y);
        a2[2] += w0 * __builtin_bit_cast(half2_t, q0.z);
        a2[3] += w0 * __builtin_bit_cast(half2_t, q0.w);
        a2[4] += w1 * __builtin_bit_cast(half2_t, q1.x);
        a2[5] += w1 * __builtin_bit_cast(half2_t, q1.y);
        a2[6] += w1 * __builtin_bit_cast(half2_t, q1.z);
        a2[7] += w1 * __builtin_bit_cast(half2_t, q1.w);
    }
    if (base < e) {
        int j0 = base + 2 * g, j1 = j0 + 1;
        uint2 pw = *(const uint2*)(cw + j0);   // in padded region; poison col < 2^17
        int c0 = (int)(pw.x >> 15);
        int c1 = (int)(pw.y >> 15);
        half2_t w0 = (j0 < e) ? dup_lo16(pw.x << 1) : (half2_t)0;
        half2_t w1 = (j1 < e) ? dup_lo16(pw.y << 1) : (half2_t)0;
        uint4 q0 = ((const uint4*)(fin + ((long)c0 << 6)))[h];
        uint4 q1 = ((const uint4*)(fin + ((long)c1 << 6)))[h];
        a2[0] += w0 * __builtin_bit_cast(half2_t, q0.x);
        a2[1] += w0 * __builtin_bit_cast(half2_t, q0.y);
        a2[2] += w0 * __builtin_bit_cast(half2_t, q0.z);
        a2[3] += w0 * __builtin_bit_cast(half2_t, q0.w);
        a2[4] += w1 * __builtin_bit_cast(half2_t, q1.x);
        a2[5] += w1 * __builtin_bit_cast(half2_t, q1.y);
        a2[6] += w1 * __builtin_bit_cast(half2_t, q1.z);
        a2[7] += w1 * __builtin_bit_cast(half2_t, q1.w);
    }

    float a[8];
    #pragma unroll
    for (int k = 0; k < 4; k++) {
        a[2 * k]     = (float)a2[k][0] + (float)a2[k + 4][0];
        a[2 * k + 1] = (float)a2[k][1] + (float)a2[k + 4][1];
    }
    #pragma unroll
    for (int k = 0; k < 8; k++) {
        a[k] += __shfl_xor(a[k], 8);
        a[k] += __shfl_xor(a[k], 16);
        a[k] += __shfl_xor(a[k], 32);
    }
    float ss = 0.0f;
    #pragma unroll
    for (int k = 0; k < 8; k++) ss += a[k] * a[k];
    ss += __shfl_xor(ss, 1);
    ss += __shfl_xor(ss, 2);
    ss += __shfl_xor(ss, 4);
    float s2 = 1.0f / fmaxf(sqrtf(ss), 1e-12f);
    if (g == 0) {
        uint4 o;
        o.x = pk_f16x2(a[0], a[1]);
        o.y = pk_f16x2(a[2], a[3]);
        o.z = pk_f16x2(a[4], a[5]);
        o.w = pk_f16x2(a[6], a[7]);
        if (writeOut) ((uint4*)(fout + ((long)wid << 6)))[h] = o;
        uint4* ap = (uint4*)(acc16 + ((long)wid << 6)) + h;
        uint4 old = *ap;
        uint4 inc;
        inc.x = pk_f16x2(a[0] * s2, a[1] * s2);
        inc.y = pk_f16x2(a[2] * s2, a[3] * s2);
        inc.z = pk_f16x2(a[4] * s2, a[5] * s2);
        inc.w = pk_f16x2(a[6] * s2, a[7] * s2);
        uint4 nw;
        nw.x = __builtin_bit_cast(unsigned int, __builtin_bit_cast(half2_t, old.x) + __builtin_bit_cast(half2_t, inc.x));
        nw.y = __builtin_bit_cast(unsigned int, __builtin_bit_cast(half2_t, old.y) + __builtin_bit_cast(half2_t, inc.y));
        nw.z = __builtin_bit_cast(unsigned int, __builtin_bit_cast(half2_t, old.z) + __builtin_bit_cast(half2_t, inc.z));
        nw.w = __builtin_bit_cast(unsigned int, __builtin_bit_cast(half2_t, old.w) + __builtin_bit_cast(half2_t, inc.w));
        *ap = nw;
    }
}

// ---- BPR loss (acc in f16) ----
__global__ void loss_terms_kernel(const unsigned short* __restrict__ acc16,
                                  const int* __restrict__ a_id, const int* __restrict__ p_id,
                                  const int* __restrict__ n_id,
                                  float* __restrict__ terms, int B) {
    long gid = (long)blockIdx.x * blockDim.x + threadIdx.x;
    int b = (int)(gid >> 6);
    int lane = threadIdx.x & 63;
    if (b < B) {
        int ia = a_id[b], ip = p_id[b], in2 = n_id[b];
        float a = (float)__builtin_bit_cast(_Float16, acc16[(long)ia * DDIM + lane]);
        float p = (float)__builtin_bit_cast(_Float16, acc16[(long)ip * DDIM + lane]);
        float n = (float)__builtin_bit_cast(_Float16, acc16[(long)in2 * DDIM + lane]);
        float dp = a * p, dn = a * n;
        #pragma unroll
        for (int off = 1; off < 64; off <<= 1) { dp += __shfl_xor(dp, off); dn += __shfl_xor(dn, off); }
        if (lane == 0) {
            float x = (dp - dn) * 0.0625f;   // node_rep = acc/4 -> preds scale 1/16
            terms[b] = fmaxf(-x, 0.0f) + log1pf(expf(-fabsf(x)));
        }
    }
}

__global__ void reduce_kernel(const float* __restrict__ terms, float* __restrict__ out, int B) {
    __shared__ float sm[256];
    float s = 0.0f;
    for (int i = threadIdx.x; i < B; i += 256) s += terms[i];
    sm[threadIdx.x] = s;
    __syncthreads();
    for (int stride = 128; stride > 0; stride >>= 1) {
        if (threadIdx.x < stride) sm[threadIdx.x] += sm[threadIdx.x + stride];
        __syncthreads();
    }
    if (threadIdx.x == 0) out[0] = sm[0] / (float)B;
}

extern "C" void kernel_launch(void* const* d_in, const int* in_sizes, int n_in,
                              void* d_out, int out_size, void* d_ws, size_t ws_size,
                              hipStream_t stream) {
    const float* nf    = (const float*)d_in[0];
    const int*   erow  = (const int*)d_in[1];
    const int*   ecol  = (const int*)d_in[2];
    const float* evals = (const float*)d_in[3];
    const int*   a_id  = (const int*)d_in[4];
    const int*   p_id  = (const int*)d_in[5];
    const int*   n_id  = (const int*)d_in[6];

    int N = in_sizes[0] / DDIM;
    int E = in_sizes[1];
    int B = in_sizes[4];
    int NB = (N + BUCKET - 1) / BUCKET;
    int chunk = (((E + NBLK - 1) / NBLK) + 3) & ~3;   // multiple of 4 -> aligned quad loads
    int Npad = NB * BUCKET;

    // bucket capacity: mean + ~8.3% + 2048 (even-rounding pad + >10 sigma)
    long capl = ((long)E * BUCKET) / N;
    int cap = (int)(capl + capl / 12 + 2048);
    cap = (cap + 63) & ~63;

    size_t brkBytes = (size_t)cap * NB * 4;
    size_t brvBytes = (size_t)cap * NB * 2;
    size_t featB16 = (size_t)N * DDIM * 2;
    size_t regionA = brkBytes + brvBytes;
    if (regionA < 2 * featB16) regionA = 2 * featB16;   // later fb0+fb1
    size_t regionB = (size_t)cap * NB * 4;              // bc (4 B), later cw (4 B)
    size_t subBytes = (size_t)NB * 8 * BUCKET * 4;

    char* w = (char*)d_ws;
    char* regAp  = w;                 w += regionA;
    unsigned int* brk = (unsigned int*)regAp;
    unsigned short* brv = (unsigned short*)(regAp + brkBytes);
    unsigned int* bc = (unsigned int*)w;
    unsigned int* cw = (unsigned int*)w;  w += regionB + 64;   // +64: spmm tail overread pad
    unsigned int* acc16 = (unsigned int*)w;  w += featB16;
    int* subcnt  = (int*)w;           w += subBytes;    // becomes pbase in combine
    float* subds = (float*)w;         w += subBytes;
    float* subdsc= (float*)w;         w += subBytes;
    float* inv_c = (float*)w;         w += (size_t)Npad * 4;
    float* inv_r = (float*)w;         w += (size_t)Npad * 4;
    int* rowstart= (int*)w;           w += (size_t)N * 4;
    int* rowend  = (int*)w;           w += (size_t)N * 4;
    int* gfill_r = (int*)w;           w += (size_t)NB * 16 * 4;
    int* gfill_c = (int*)w;           w += (size_t)NB * 16 * 4;
    float* terms = (float*)w;         w += (size_t)B * 4;

    unsigned short* fb0 = (unsigned short*)regAp;             // aliases brk/brv (dead after place)
    unsigned short* fb1 = (unsigned short*)(regAp + featB16);

    init_fill_kernel<<<1, 128, 0, stream>>>(gfill_r, gfill_c, NB, cap);
    binning_kernel<<<NBLK, TPB_BIN, 0, stream>>>(erow, ecol, evals, gfill_r, gfill_c,
                                                 brk, brv, bc, E, NB, chunk);
    count_kernel<<<NB * 8, TPB_CP, 0, stream>>>(brk, brv, bc, gfill_r, gfill_c,
                                                subcnt, subds, subdsc, cap);
    combine_kernel<<<NB, 1024, 0, stream>>>(subcnt, subds, subdsc, rowstart, rowend,
                                            inv_r, inv_c, N, cap);
    place_kernel<<<NB * 8, TPB_CP, 0, stream>>>(brk, brv, gfill_r, subcnt, inv_r, inv_c, cw, cap);

    long n4 = (long)N * DDIM / 4;
    cvt_kernel<<<(unsigned)((n4 + 255) / 256), 256, 0, stream>>>(nf, acc16, (unsigned int*)fb0, n4);

    unsigned spmmGrid = (unsigned)((N + 3) / 4);   // 4 waves (rows) per 256-thread block
    spmm_f16_kernel<<<spmmGrid, 256, 0, stream>>>(rowstart, rowend, cw, fb0, fb1,
                                                  (unsigned short*)acc16, N, 1);
    spmm_f16_kernel<<<spmmGrid, 256, 0, stream>>>(rowstart, rowend, cw, fb1, fb0,
                                                  (unsigned short*)acc16, N, 1);
    spmm_f16_kernel<<<spmmGrid, 256, 0, stream>>>(rowstart, rowend, cw, fb0, fb1,
                                                  (unsigned short*)acc16, N, 0);

    loss_terms_kernel<<<(unsigned)(((long)B * 64 + 255) / 256), 256, 0, stream>>>(
        (const unsigned short*)acc16, a_id, p_id, n_id, terms, B);
    reduce_kernel<<<1, 256, 0, stream>>>(terms, (float*)d_out, B);
}

// Round 16
// 418.657 us; speedup vs baseline: 1.0955x; 1.0138x over previous
//
#include <hip/hip_runtime.h>
#include <math.h>

#define DDIM 64
#define BUCKET 1024             // nodes per binning bucket
#define LRSHIFT 17              // br-packed: col [0,17), lrow [17,27), val [32,64)
#define CMASK 0x1FFFF
#define LRMASK 0x3FF
#define NBLK 512
#define TPB_BIN 1024
#define NWV 16                  // waves per binning block
#define TPB_CP 512
#define MAXNB 128               // max buckets (NB = ceil(100000/1024) = 98)

typedef unsigned long long ull;
typedef _Float16 half2_t __attribute__((ext_vector_type(2)));

__device__ inline unsigned int bf16_hi(float v) {       // RNE bf16 bits in high 16
    unsigned int a = __float_as_uint(v);
    return (a + 0x7fffu + ((a >> 16) & 1u)) & 0xffff0000u;
}

__device__ inline unsigned int pk_f16x2(float lo, float hi) {
    return __builtin_bit_cast(unsigned int, __builtin_amdgcn_cvt_pkrtz(lo, hi));
}

__device__ inline half2_t dup_lo16(unsigned int s) {    // (s&0xFFFF) in both halves
    return __builtin_bit_cast(half2_t, __builtin_amdgcn_perm(0u, s, 0x01000100u));
}

__device__ inline half2_t h2_shfl_xor(half2_t v, int off) {
    return __builtin_bit_cast(half2_t, __shfl_xor(__builtin_bit_cast(unsigned int, v), off));
}

// ---- init global fill counters (cacheline-padded: stride 16 ints) ----
__global__ void init_fill_kernel(int* __restrict__ gfill_r, int* __restrict__ gfill_c,
                                 int NB, int cap) {
    int k = blockIdx.x * blockDim.x + threadIdx.x;
    if (k < NB) {
        gfill_r[k * 16] = k * cap;
        gfill_c[k * 16] = k * cap;
    }
}

// ---- fused binning: 16 per-wave count hists, BLOCK-level reserve+cursors, 4-edge ILP ----
__global__ __launch_bounds__(TPB_BIN)
void binning_kernel(const int* __restrict__ erow, const int* __restrict__ ecol,
                    const float* __restrict__ evals,
                    int* __restrict__ gfill_r, int* __restrict__ gfill_c,
                    ull* __restrict__ br, unsigned int* __restrict__ bc,
                    int E, int NB, int chunk) {
    __shared__ int hr[NWV][MAXNB];
    __shared__ int hc[NWV][MAXNB];
    __shared__ int fr[MAXNB];     // block-level fill cursors (row key)
    __shared__ int fc[MAXNB];     // block-level fill cursors (col key)
    int t = threadIdx.x;
    int wv = t >> 6;
    for (int k = t; k < NWV * MAXNB; k += TPB_BIN) { (&hr[0][0])[k] = 0; (&hc[0][0])[k] = 0; }
    __syncthreads();
    int lo = blockIdx.x * chunk;             // chunk multiple of 4 -> lo 16B-aligned
    int hi = min(E, lo + chunk);
    int nq = (hi - lo) >> 2;
    int rem = (hi - lo) & 3;
    // phase 1: per-wave count, 4 edges per thread
    for (int p = t; p < nq; p += TPB_BIN) {
        int i = lo + 4 * p;
        int4 r4 = *(const int4*)(erow + i);
        int4 c4 = *(const int4*)(ecol + i);
        atomicAdd(&hr[wv][r4.x >> 10], 1);
        atomicAdd(&hr[wv][r4.y >> 10], 1);
        atomicAdd(&hr[wv][r4.z >> 10], 1);
        atomicAdd(&hr[wv][r4.w >> 10], 1);
        atomicAdd(&hc[wv][c4.x >> 10], 1);
        atomicAdd(&hc[wv][c4.y >> 10], 1);
        atomicAdd(&hc[wv][c4.z >> 10], 1);
        atomicAdd(&hc[wv][c4.w >> 10], 1);
    }
    if (t == 0) {
        for (int i = hi - rem; i < hi; i++) {
            atomicAdd(&hr[0][erow[i] >> 10], 1);
            atomicAdd(&hc[0][ecol[i] >> 10], 1);
        }
    }
    __syncthreads();
    // phase 2: ONE reservation per (block,bucket) -> long contiguous output runs
    if (t < NB) {
        int sr = 0, sc = 0;
        #pragma unroll
        for (int w2 = 0; w2 < NWV; w2++) { sr += hr[w2][t]; sc += hc[w2][t]; }
        fr[t] = atomicAdd(&gfill_r[t * 16], sr);
        fc[t] = atomicAdd(&gfill_c[t * 16], sc);
    }
    __syncthreads();
    // phase 3: place 4 edges per thread with BLOCK-shared cursors (8 B br store)
    for (int p = t; p < nq; p += TPB_BIN) {
        int i = lo + 4 * p;
        int4 r4 = *(const int4*)(erow + i);
        int4 c4 = *(const int4*)(ecol + i);
        float4 v4 = *(const float4*)(evals + i);
        int pos0 = atomicAdd(&fr[r4.x >> 10], 1);
        int pos1 = atomicAdd(&fr[r4.y >> 10], 1);
        int pos2 = atomicAdd(&fr[r4.z >> 10], 1);
        int pos3 = atomicAdd(&fr[r4.w >> 10], 1);
        br[pos0] = ((ull)__float_as_uint(v4.x) << 32) | ((ull)(r4.x & 1023) << LRSHIFT) | (unsigned)c4.x;
        br[pos1] = ((ull)__float_as_uint(v4.y) << 32) | ((ull)(r4.y & 1023) << LRSHIFT) | (unsigned)c4.y;
        br[pos2] = ((ull)__float_as_uint(v4.z) << 32) | ((ull)(r4.z & 1023) << LRSHIFT) | (unsigned)c4.z;
        br[pos3] = ((ull)__float_as_uint(v4.w) << 32) | ((ull)(r4.w & 1023) << LRSHIFT) | (unsigned)c4.w;
        int q0 = atomicAdd(&fc[c4.x >> 10], 1);
        int q1 = atomicAdd(&fc[c4.y >> 10], 1);
        int q2 = atomicAdd(&fc[c4.z >> 10], 1);
        int q3 = atomicAdd(&fc[c4.w >> 10], 1);
        bc[q0] = bf16_hi(v4.x) | (unsigned)(c4.x & 1023);
        bc[q1] = bf16_hi(v4.y) | (unsigned)(c4.y & 1023);
        bc[q2] = bf16_hi(v4.z) | (unsigned)(c4.z & 1023);
        bc[q3] = bf16_hi(v4.w) | (unsigned)(c4.w & 1023);
    }
    if (t == 0) {
        for (int i = hi - rem; i < hi; i++) {
            int r = erow[i], c = ecol[i];
            float v = evals[i];
            int pos = atomicAdd(&fr[r >> 10], 1);
            br[pos] = ((ull)__float_as_uint(v) << 32) | ((ull)(r & 1023) << LRSHIFT) | (unsigned)c;
            int pos2 = atomicAdd(&fc[c >> 10], 1);
            bc[pos2] = bf16_hi(v) | (unsigned)(c & 1023);
        }
    }
}

// ---- count: block (bucket b, chunk ch) reads its 1/8 edge slice ONCE, 2-edge ILP ----
__global__ __launch_bounds__(TPB_CP)
void count_kernel(const ull* __restrict__ br, const unsigned int* __restrict__ bc,
                  const int* __restrict__ gfill_r, const int* __restrict__ gfill_c,
                  int* __restrict__ subcnt, float* __restrict__ subds,
                  float* __restrict__ subdsc, int cap) {
    __shared__ int cnt[BUCKET];
    __shared__ float ds[BUCKET];
    __shared__ float dsc[BUCKET];
    int b = blockIdx.x >> 3, ch = blockIdx.x & 7;
    int t = threadIdx.x;
    for (int k = t; k < BUCKET; k += TPB_CP) { cnt[k] = 0; ds[k] = 0.0f; dsc[k] = 0.0f; }
    __syncthreads();
    int s = b * cap;                              // cap mult of 64 -> s even
    int e = gfill_r[b * 16];
    int len = ((((e - s) + 7) >> 3) + 1) & ~1;    // even slice length
    int cs = s + ch * len, ce = min(e, cs + len);
    int m = cs + ((ce - cs) & ~1);
    for (int i = cs + 2 * t; i < m; i += 2 * TPB_CP) {
        ull p0 = br[i];
        ull p1 = br[i + 1];
        int lr0 = (int)((p0 >> LRSHIFT) & LRMASK);
        int lr1 = (int)((p1 >> LRSHIFT) & LRMASK);
        atomicAdd(&cnt[lr0], 1);
        atomicAdd(&cnt[lr1], 1);
        atomicAdd(&ds[lr0], __uint_as_float((unsigned)(p0 >> 32)));
        atomicAdd(&ds[lr1], __uint_as_float((unsigned)(p1 >> 32)));
    }
    if (t == 0 && m < ce) {
        ull p = br[m];
        int lr = (int)((p >> LRSHIFT) & LRMASK);
        atomicAdd(&cnt[lr], 1);
        atomicAdd(&ds[lr], __uint_as_float((unsigned)(p >> 32)));
    }
    int e2 = gfill_c[b * 16];
    int len2 = ((((e2 - s) + 7) >> 3) + 1) & ~1;
    int cs2 = s + ch * len2, ce2 = min(e2, cs2 + len2);
    int m2 = cs2 + ((ce2 - cs2) & ~1);
    for (int i = cs2 + 2 * t; i < m2; i += 2 * TPB_CP) {
        uint2 p = *(const uint2*)(bc + i);
        atomicAdd(&dsc[p.x & 0x3FFu], __uint_as_float(p.x & 0xffff0000u));
        atomicAdd(&dsc[p.y & 0x3FFu], __uint_as_float(p.y & 0xffff0000u));
    }
    if (t == 0 && m2 < ce2) {
        unsigned int p = bc[m2];
        atomicAdd(&dsc[p & 0x3FFu], __uint_as_float(p & 0xffff0000u));
    }
    __syncthreads();
    size_t base = ((size_t)b * 8 + ch) * BUCKET;
    for (int k = t; k < BUCKET; k += TPB_CP) {
        subcnt[base + k] = cnt[k];
        subds[base + k]  = ds[k];
        subdsc[base + k] = dsc[k];
    }
}

// ---- combine: even-rounded scan -> rse (int2), per-chunk bases, inv_r, inv_c ----
__global__ __launch_bounds__(1024)
void combine_kernel(int* __restrict__ subcnt, const float* __restrict__ subds,
                    const float* __restrict__ subdsc,
                    int2* __restrict__ rse,
                    float* __restrict__ inv_r, float* __restrict__ inv_c,
                    int N, int cap) {
    __shared__ int tot[BUCKET];
    int b = blockIdx.x, t = threadIdx.x;
    size_t base = (size_t)b * 8 * BUCKET;
    int c8[8];
    int sum = 0;
    #pragma unroll
    for (int c = 0; c < 8; c++) { c8[c] = subcnt[base + c * BUCKET + t]; sum += c8[c]; }
    int sum2 = (sum + 1) & ~1;           // even-rounded slot count -> even row starts
    tot[t] = sum2;
    __syncthreads();
    for (int off = 1; off < BUCKET; off <<= 1) {
        int v = (t >= off) ? tot[t - off] : 0;
        __syncthreads();
        tot[t] += v;
        __syncthreads();
    }
    int excl = tot[t] - sum2;
    int node = b * BUCKET + t;
    int s = b * cap;
    if (node < N) {
        int2 se;
        se.x = s + excl;
        se.y = s + excl + sum;
        rse[node] = se;
    }
    int run = s + excl;
    #pragma unroll
    for (int c = 0; c < 8; c++) { int v = c8[c]; subcnt[base + c * BUCKET + t] = run; run += v; }
    float d = 0.0f, dc = 0.0f;
    #pragma unroll
    for (int c = 0; c < 8; c++) { d += subds[base + c * BUCKET + t]; dc += subdsc[base + c * BUCKET + t]; }
    inv_r[b * BUCKET + t] = 1.0f / (sqrtf(d) + 1e-8f);
    inv_c[b * BUCKET + t] = 1.0f / (sqrtf(dc) + 1e-8f);
}

// ---- place: ranked placement, 2-edge ILP; 4 B entry = col<<15 | f16w>>1 ----
__global__ __launch_bounds__(TPB_CP)
void place_kernel(const ull* __restrict__ br, const int* __restrict__ gfill_r,
                  const int* __restrict__ pbase, const float* __restrict__ inv_r,
                  const float* __restrict__ inv_c,
                  unsigned int* __restrict__ cw, int cap) {
    __shared__ int fill[BUCKET];
    __shared__ float irs[BUCKET];
    int b = blockIdx.x >> 3, ch = blockIdx.x & 7;
    int t = threadIdx.x;
    size_t pb = ((size_t)b * 8 + ch) * BUCKET;
    for (int k = t; k < BUCKET; k += TPB_CP) {
        fill[k] = pbase[pb + k];
        irs[k]  = inv_r[b * BUCKET + k];
    }
    __syncthreads();
    int s = b * cap;
    int e = gfill_r[b * 16];
    int len = ((((e - s) + 7) >> 3) + 1) & ~1;
    int cs = s + ch * len, ce = min(e, cs + len);
    int m = cs + ((ce - cs) & ~1);
    for (int i = cs + 2 * t; i < m; i += 2 * TPB_CP) {
        ull p0 = br[i];
        ull p1 = br[i + 1];
        int c0 = (int)(p0 & CMASK), c1 = (int)(p1 & CMASK);
        int lr0 = (int)((p0 >> LRSHIFT) & LRMASK);
        int lr1 = (int)((p1 >> LRSHIFT) & LRMASK);
        float v0 = __uint_as_float((unsigned)(p0 >> 32));
        float v1 = __uint_as_float((unsigned)(p1 >> 32));
        int pos0 = atomicAdd(&fill[lr0], 1);
        int pos1 = atomicAdd(&fill[lr1], 1);
        float w0 = v0 * inv_c[c0] * irs[lr0];
        float w1 = v1 * inv_c[c1] * irs[lr1];
        cw[pos0] = ((unsigned)c0 << 15) | ((pk_f16x2(w0, w0) & 0xFFFFu) >> 1);
        cw[pos1] = ((unsigned)c1 << 15) | ((pk_f16x2(w1, w1) & 0xFFFFu) >> 1);
    }
    if (t == 0 && m < ce) {
        ull p = br[m];
        int c = (int)(p & CMASK);
        int lr = (int)((p >> LRSHIFT) & LRMASK);
        float v = __uint_as_float((unsigned)(p >> 32));
        int pos = atomicAdd(&fill[lr], 1);
        float wv = v * inv_c[c] * irs[lr];
        cw[pos] = ((unsigned)c << 15) | ((pk_f16x2(wv, wv) & 0xFFFFu) >> 1);
    }
}

// ---- fused: acc16 = f16(nf), fb0 = f16(nf); 4 floats/thread ----
__global__ void cvt_kernel(const float* __restrict__ src, unsigned int* __restrict__ acc16,
                           unsigned int* __restrict__ dst, long n4) {
    long i = (long)blockIdx.x * blockDim.x + threadIdx.x;
    if (i < n4) {
        float4 v = ((const float4*)src)[i];
        uint2 o;
        o.x = pk_f16x2(v.x, v.y);
        o.y = pk_f16x2(v.z, v.w);
        ((uint2*)acc16)[i] = o;
        ((uint2*)dst)[i] = o;
    }
}

// ---- SpMM: wave per row, uint2 cw pairs, v_pk_fma_f16, packed-f16 epilogue ----
__global__ __launch_bounds__(256)
void spmm_f16_kernel(const int2* __restrict__ rse,
                     const unsigned int* __restrict__ cw,
                     const unsigned short* __restrict__ fin,
                     unsigned short* __restrict__ fout,
                     unsigned short* __restrict__ acc16, int N, int writeOut) {
    int wid = blockIdx.x * (blockDim.x >> 6) + (threadIdx.x >> 6);   // row
    if (wid >= N) return;
    int lane = threadIdx.x & 63;
    int g = lane >> 3;          // edge-pair slot 0..7 (16 edges per iteration)
    int h = lane & 7;           // feature chunk (8 f16 = 16 B)
    int2 se = rse[wid];
    int s = se.x, e = se.y;     // s even -> uint2-aligned cw pairs
    half2_t a2[8];
    #pragma unroll
    for (int k = 0; k < 8; k++) a2[k] = (half2_t)0;

    int nfull = (e - s) >> 4;
    int base = s;
    for (int it = 0; it < nfull; it++, base += 16) {
        int j0 = base + 2 * g;
        uint2 pw = *(const uint2*)(cw + j0);
        int c0 = (int)(pw.x >> 15);
        int c1 = (int)(pw.y >> 15);
        uint4 q0 = ((const uint4*)(fin + ((long)c0 << 6)))[h];
        uint4 q1 = ((const uint4*)(fin + ((long)c1 << 6)))[h];
        half2_t w0 = dup_lo16(pw.x << 1);
        half2_t w1 = dup_lo16(pw.y << 1);
        a2[0] += w0 * __builtin_bit_cast(half2_t, q0.x);
        a2[1] += w0 * __builtin_bit_cast(half2_t, q0.y);
        a2[2] += w0 * __builtin_bit_cast(half2_t, q0.z);
        a2[3] += w0 * __builtin_bit_cast(half2_t, q0.w);
        a2[4] += w1 * __builtin_bit_cast(half2_t, q1.x);
        a2[5] += w1 * __builtin_bit_cast(half2_t, q1.y);
        a2[6] += w1 * __builtin_bit_cast(half2_t, q1.z);
        a2[7] += w1 * __builtin_bit_cast(half2_t, q1.w);
    }
    if (base < e) {
        int j0 = base + 2 * g, j1 = j0 + 1;
        uint2 pw = *(const uint2*)(cw + j0);   // in padded region; poison col < 2^17
        int c0 = (int)(pw.x >> 15);
        int c1 = (int)(pw.y >> 15);
        half2_t w0 = (j0 < e) ? dup_lo16(pw.x << 1) : (half2_t)0;
        half2_t w1 = (j1 < e) ? dup_lo16(pw.y << 1) : (half2_t)0;
        uint4 q0 = ((const uint4*)(fin + ((long)c0 << 6)))[h];
        uint4 q1 = ((const uint4*)(fin + ((long)c1 << 6)))[h];
        a2[0] += w0 * __builtin_bit_cast(half2_t, q0.x);
        a2[1] += w0 * __builtin_bit_cast(half2_t, q0.y);
        a2[2] += w0 * __builtin_bit_cast(half2_t, q0.z);
        a2[3] += w0 * __builtin_bit_cast(half2_t, q0.w);
        a2[4] += w1 * __builtin_bit_cast(half2_t, q1.x);
        a2[5] += w1 * __builtin_bit_cast(half2_t, q1.y);
        a2[6] += w1 * __builtin_bit_cast(half2_t, q1.z);
        a2[7] += w1 * __builtin_bit_cast(half2_t, q1.w);
    }

    // packed-f16 epilogue: parity combine (4), g-reduce (12 shfl + 12 add)
    #pragma unroll
    for (int k = 0; k < 4; k++) a2[k] += a2[k + 4];
    #pragma unroll
    for (int k = 0; k < 4; k++) {
        a2[k] += h2_shfl_xor(a2[k], 8);
        a2[k] += h2_shfl_xor(a2[k], 16);
        a2[k] += h2_shfl_xor(a2[k], 32);
    }
    // sum of squares in f16 pairs, finish in f32
    half2_t ssh = a2[0] * a2[0];
    ssh += a2[1] * a2[1];
    ssh += a2[2] * a2[2];
    ssh += a2[3] * a2[3];
    float ss = (float)ssh[0] + (float)ssh[1];
    ss += __shfl_xor(ss, 1);
    ss += __shfl_xor(ss, 2);
    ss += __shfl_xor(ss, 4);
    float s2 = fminf(1.0f / fmaxf(sqrtf(ss), 1e-12f), 6.0e4f);  // clamp: f16-safe
    if (g == 0) {
        if (writeOut) {
            uint4 o;
            o.x = __builtin_bit_cast(unsigned int, a2[0]);
            o.y = __builtin_bit_cast(unsigned int, a2[1]);
            o.z = __builtin_bit_cast(unsigned int, a2[2]);
            o.w = __builtin_bit_cast(unsigned int, a2[3]);
            ((uint4*)(fout + ((long)wid << 6)))[h] = o;
        }
        half2_t s2h = __builtin_bit_cast(half2_t, pk_f16x2(s2, s2));
        uint4* ap = (uint4*)(acc16 + ((long)wid << 6)) + h;
        uint4 old = *ap;
        uint4 nw;
        nw.x = __builtin_bit_cast(unsigned int, __builtin_bit_cast(half2_t, old.x) + a2[0] * s2h);
        nw.y = __builtin_bit_cast(unsigned int, __builtin_bit_cast(half2_t, old.y) + a2[1] * s2h);
        nw.z = __builtin_bit_cast(unsigned int, __builtin_bit_cast(half2_t, old.z) + a2[2] * s2h);
        nw.w = __builtin_bit_cast(unsigned int, __builtin_bit_cast(half2_t, old.w) + a2[3] * s2h);
        *ap = nw;
    }
}

// ---- BPR loss (acc in f16) ----
__global__ void loss_terms_kernel(const unsigned short* __restrict__ acc16,
                                  const int* __restrict__ a_id, const int* __restrict__ p_id,
                                  const int* __restrict__ n_id,
                                  float* __restrict__ terms, int B) {
    long gid = (long)blockIdx.x * blockDim.x + threadIdx.x;
    int b = (int)(gid >> 6);
    int lane = threadIdx.x & 63;
    if (b < B) {
        int ia = a_id[b], ip = p_id[b], in2 = n_id[b];
        float a = (float)__builtin_bit_cast(_Float16, acc16[(long)ia * DDIM + lane]);
        float p = (float)__builtin_bit_cast(_Float16, acc16[(long)ip * DDIM + lane]);
        float n = (float)__builtin_bit_cast(_Float16, acc16[(long)in2 * DDIM + lane]);
        float dp = a * p, dn = a * n;
        #pragma unroll
        for (int off = 1; off < 64; off <<= 1) { dp += __shfl_xor(dp, off); dn += __shfl_xor(dn, off); }
        if (lane == 0) {
            float x = (dp - dn) * 0.0625f;   // node_rep = acc/4 -> preds scale 1/16
            terms[b] = fmaxf(-x, 0.0f) + log1pf(expf(-fabsf(x)));
        }
    }
}

__global__ void reduce_kernel(const float* __restrict__ terms, float* __restrict__ out, int B) {
    __shared__ float sm[256];
    float s = 0.0f;
    for (int i = threadIdx.x; i < B; i += 256) s += terms[i];
    sm[threadIdx.x] = s;
    __syncthreads();
    for (int stride = 128; stride > 0; stride >>= 1) {
        if (threadIdx.x < stride) sm[threadIdx.x] += sm[threadIdx.x + stride];
        __syncthreads();
    }
    if (threadIdx.x == 0) out[0] = sm[0] / (float)B;
}

extern "C" void kernel_launch(void* const* d_in, const int* in_sizes, int n_in,
                              void* d_out, int out_size, void* d_ws, size_t ws_size,
                              hipStream_t stream) {
    const float* nf    = (const float*)d_in[0];
    const int*   erow  = (const int*)d_in[1];
    const int*   ecol  = (const int*)d_in[2];
    const float* evals = (const float*)d_in[3];
    const int*   a_id  = (const int*)d_in[4];
    const int*   p_id  = (const int*)d_in[5];
    const int*   n_id  = (const int*)d_in[6];

    int N = in_sizes[0] / DDIM;
    int E = in_sizes[1];
    int B = in_sizes[4];
    int NB = (N + BUCKET - 1) / BUCKET;
    int chunk = (((E + NBLK - 1) / NBLK) + 3) & ~3;   // multiple of 4 -> aligned quad loads
    int Npad = NB * BUCKET;

    // bucket capacity: mean + ~8.3% + 2048 (even-rounding pad + >10 sigma)
    long capl = ((long)E * BUCKET) / N;
    int cap = (int)(capl + capl / 12 + 2048);
    cap = (cap + 63) & ~63;

    size_t regionA = (size_t)cap * NB * 8;            // br (8 B), later fb0+fb1
    size_t regionB = (size_t)cap * NB * 4;            // bc (4 B), later cw (4 B)
    size_t featB16 = (size_t)N * DDIM * 2;
    if (regionA < 2 * featB16) regionA = 2 * featB16;
    size_t subBytes = (size_t)NB * 8 * BUCKET * 4;

    char* w = (char*)d_ws;
    ull*  br     = (ull*)w;
    char* regAp  = w;                 w += regionA;
    unsigned int* bc = (unsigned int*)w;
    unsigned int* cw = (unsigned int*)w;  w += regionB + 64;   // +64: spmm tail overread pad
    unsigned int* acc16 = (unsigned int*)w;  w += featB16;
    int* subcnt  = (int*)w;           w += subBytes;    // becomes pbase in combine
    float* subds = (float*)w;         w += subBytes;
    float* subdsc= (float*)w;         w += subBytes;
    float* inv_c = (float*)w;         w += (size_t)Npad * 4;
    float* inv_r = (float*)w;         w += (size_t)Npad * 4;
    int2* rse    = (int2*)w;          w += (size_t)N * 8;
    int* gfill_r = (int*)w;           w += (size_t)NB * 16 * 4;
    int* gfill_c = (int*)w;           w += (size_t)NB * 16 * 4;
    float* terms = (float*)w;         w += (size_t)B * 4;

    unsigned short* fb0 = (unsigned short*)regAp;             // aliases br (dead after place)
    unsigned short* fb1 = (unsigned short*)(regAp + featB16);

    init_fill_kernel<<<1, 128, 0, stream>>>(gfill_r, gfill_c, NB, cap);
    binning_kernel<<<NBLK, TPB_BIN, 0, stream>>>(erow, ecol, evals, gfill_r, gfill_c,
                                                 br, bc, E, NB, chunk);
    count_kernel<<<NB * 8, TPB_CP, 0, stream>>>(br, bc, gfill_r, gfill_c,
                                                subcnt, subds, subdsc, cap);
    combine_kernel<<<NB, 1024, 0, stream>>>(subcnt, subds, subdsc, rse,
                                            inv_r, inv_c, N, cap);
    place_kernel<<<NB * 8, TPB_CP, 0, stream>>>(br, gfill_r, subcnt, inv_r, inv_c, cw, cap);

    long n4 = (long)N * DDIM / 4;
    cvt_kernel<<<(unsigned)((n4 + 255) / 256), 256, 0, stream>>>(nf, acc16, (unsigned int*)fb0, n4);

    unsigned spmmGrid = (unsigned)((N + 3) / 4);   // 4 waves (rows) per 256-thread block
    spmm_f16_kernel<<<spmmGrid, 256, 0, stream>>>(rse, cw, fb0, fb1,
                                                  (unsigned short*)acc16, N, 1);
    spmm_f16_kernel<<<spmmGrid, 256, 0, stream>>>(rse, cw, fb1, fb0,
                                                  (unsigned short*)acc16, N, 1);
    spmm_f16_kernel<<<spmmGrid, 256, 0, stream>>>(rse, cw, fb0, fb1,
                                                  (unsigned short*)acc16, N, 0);

    loss_terms_kernel<<<(unsigned)(((long)B * 64 + 255) / 256), 256, 0, stream>>>(
        (const unsigned short*)acc16, a_id, p_id, n_id, terms, B);
    reduce_kernel<<<1, 256, 0, stream>>>(terms, (float*)d_out, B);
}

// Round 17
// 405.313 us; speedup vs baseline: 1.1316x; 1.0329x over previous
//
#include <hip/hip_runtime.h>
#include <math.h>

#define DDIM 64
#define BUCKET 1024             // nodes per binning bucket
#define LRSHIFT 17              // br-packed: col [0,17), lrow [17,27), val [32,64)
#define CMASK 0x1FFFF
#define LRMASK 0x3FF
#define NBLK 512
#define TPB_BIN 1024
#define NWV 16                  // waves per binning block
#define TPB_CP 512
#define MAXNB 128               // max buckets (NB = ceil(100000/1024) = 98)

typedef unsigned long long ull;
typedef _Float16 half2_t __attribute__((ext_vector_type(2)));

__device__ inline unsigned int bf16_hi(float v) {       // RNE bf16 bits in high 16
    unsigned int a = __float_as_uint(v);
    return (a + 0x7fffu + ((a >> 16) & 1u)) & 0xffff0000u;
}

__device__ inline unsigned int pk_f16x2(float lo, float hi) {
    return __builtin_bit_cast(unsigned int, __builtin_amdgcn_cvt_pkrtz(lo, hi));
}

__device__ inline half2_t dup_lo16(unsigned int s) {    // (s&0xFFFF) in both halves
    return __builtin_bit_cast(half2_t, __builtin_amdgcn_perm(0u, s, 0x01000100u));
}

__device__ inline half2_t h2_shfl_xor(half2_t v, int off) {
    return __builtin_bit_cast(half2_t, __shfl_xor(__builtin_bit_cast(unsigned int, v), off));
}

// ---- init global fill counters (cacheline-padded: stride 16 ints) ----
__global__ void init_fill_kernel(int* __restrict__ gfill_r, int* __restrict__ gfill_c,
                                 int NB, int cap) {
    int k = blockIdx.x * blockDim.x + threadIdx.x;
    if (k < NB) {
        gfill_r[k * 16] = k * cap;
        gfill_c[k * 16] = k * cap;
    }
}

// ---- fused binning: per-wave count, block reserve, REGISTER-CACHED place ----
__global__ __launch_bounds__(TPB_BIN)
void binning_kernel(const int* __restrict__ erow, const int* __restrict__ ecol,
                    const float* __restrict__ evals,
                    int* __restrict__ gfill_r, int* __restrict__ gfill_c,
                    ull* __restrict__ br, unsigned int* __restrict__ bc,
                    int E, int NB, int chunk) {
    __shared__ int hr[NWV][MAXNB];
    __shared__ int hc[NWV][MAXNB];
    __shared__ int fr[MAXNB];     // block-level fill cursors (row key)
    __shared__ int fc[MAXNB];     // block-level fill cursors (col key)
    int t = threadIdx.x;
    int wv = t >> 6;
    for (int k = t; k < NWV * MAXNB; k += TPB_BIN) { (&hr[0][0])[k] = 0; (&hc[0][0])[k] = 0; }
    __syncthreads();
    int lo = blockIdx.x * chunk;             // chunk multiple of 4 -> lo 16B-aligned
    int hi = min(E, lo + chunk);
    int nq = (hi - lo) >> 2;
    int rem = (hi - lo) & 3;
    // phase 1: per-wave count; cache edge data in registers (chunk <= 8*TPB -> <=2 iters)
    int p0 = t, p1 = t + TPB_BIN;
    bool h0 = p0 < nq, h1 = p1 < nq;
    int4 r40, c40, r41, c41;
    float4 v40, v41;
    if (h0) {
        int i = lo + 4 * p0;
        r40 = *(const int4*)(erow + i);
        c40 = *(const int4*)(ecol + i);
        v40 = *(const float4*)(evals + i);
        atomicAdd(&hr[wv][r40.x >> 10], 1);
        atomicAdd(&hr[wv][r40.y >> 10], 1);
        atomicAdd(&hr[wv][r40.z >> 10], 1);
        atomicAdd(&hr[wv][r40.w >> 10], 1);
        atomicAdd(&hc[wv][c40.x >> 10], 1);
        atomicAdd(&hc[wv][c40.y >> 10], 1);
        atomicAdd(&hc[wv][c40.z >> 10], 1);
        atomicAdd(&hc[wv][c40.w >> 10], 1);
    }
    if (h1) {
        int i = lo + 4 * p1;
        r41 = *(const int4*)(erow + i);
        c41 = *(const int4*)(ecol + i);
        v41 = *(const float4*)(evals + i);
        atomicAdd(&hr[wv][r41.x >> 10], 1);
        atomicAdd(&hr[wv][r41.y >> 10], 1);
        atomicAdd(&hr[wv][r41.z >> 10], 1);
        atomicAdd(&hr[wv][r41.w >> 10], 1);
        atomicAdd(&hc[wv][c41.x >> 10], 1);
        atomicAdd(&hc[wv][c41.y >> 10], 1);
        atomicAdd(&hc[wv][c41.z >> 10], 1);
        atomicAdd(&hc[wv][c41.w >> 10], 1);
    }
    if (t == 0) {
        for (int i = hi - rem; i < hi; i++) {
            atomicAdd(&hr[0][erow[i] >> 10], 1);
            atomicAdd(&hc[0][ecol[i] >> 10], 1);
        }
    }
    __syncthreads();
    // phase 2: ONE reservation per (block,bucket) -> long contiguous output runs
    if (t < NB) {
        int sr = 0, sc = 0;
        #pragma unroll
        for (int w2 = 0; w2 < NWV; w2++) { sr += hr[w2][t]; sc += hc[w2][t]; }
        fr[t] = atomicAdd(&gfill_r[t * 16], sr);
        fc[t] = atomicAdd(&gfill_c[t * 16], sc);
    }
    __syncthreads();
    // phase 3: place from registers (no global re-read)
    if (h0) {
        int pos0 = atomicAdd(&fr[r40.x >> 10], 1);
        int pos1 = atomicAdd(&fr[r40.y >> 10], 1);
        int pos2 = atomicAdd(&fr[r40.z >> 10], 1);
        int pos3 = atomicAdd(&fr[r40.w >> 10], 1);
        br[pos0] = ((ull)__float_as_uint(v40.x) << 32) | ((ull)(r40.x & 1023) << LRSHIFT) | (unsigned)c40.x;
        br[pos1] = ((ull)__float_as_uint(v40.y) << 32) | ((ull)(r40.y & 1023) << LRSHIFT) | (unsigned)c40.y;
        br[pos2] = ((ull)__float_as_uint(v40.z) << 32) | ((ull)(r40.z & 1023) << LRSHIFT) | (unsigned)c40.z;
        br[pos3] = ((ull)__float_as_uint(v40.w) << 32) | ((ull)(r40.w & 1023) << LRSHIFT) | (unsigned)c40.w;
        int q0 = atomicAdd(&fc[c40.x >> 10], 1);
        int q1 = atomicAdd(&fc[c40.y >> 10], 1);
        int q2 = atomicAdd(&fc[c40.z >> 10], 1);
        int q3 = atomicAdd(&fc[c40.w >> 10], 1);
        bc[q0] = bf16_hi(v40.x) | (unsigned)(c40.x & 1023);
        bc[q1] = bf16_hi(v40.y) | (unsigned)(c40.y & 1023);
        bc[q2] = bf16_hi(v40.z) | (unsigned)(c40.z & 1023);
        bc[q3] = bf16_hi(v40.w) | (unsigned)(c40.w & 1023);
    }
    if (h1) {
        int pos0 = atomicAdd(&fr[r41.x >> 10], 1);
        int pos1 = atomicAdd(&fr[r41.y >> 10], 1);
        int pos2 = atomicAdd(&fr[r41.z >> 10], 1);
        int pos3 = atomicAdd(&fr[r41.w >> 10], 1);
        br[pos0] = ((ull)__float_as_uint(v41.x) << 32) | ((ull)(r41.x & 1023) << LRSHIFT) | (unsigned)c41.x;
        br[pos1] = ((ull)__float_as_uint(v41.y) << 32) | ((ull)(r41.y & 1023) << LRSHIFT) | (unsigned)c41.y;
        br[pos2] = ((ull)__float_as_uint(v41.z) << 32) | ((ull)(r41.z & 1023) << LRSHIFT) | (unsigned)c41.z;
        br[pos3] = ((ull)__float_as_uint(v41.w) << 32) | ((ull)(r41.w & 1023) << LRSHIFT) | (unsigned)c41.w;
        int q0 = atomicAdd(&fc[c41.x >> 10], 1);
        int q1 = atomicAdd(&fc[c41.y >> 10], 1);
        int q2 = atomicAdd(&fc[c41.z >> 10], 1);
        int q3 = atomicAdd(&fc[c41.w >> 10], 1);
        bc[q0] = bf16_hi(v41.x) | (unsigned)(c41.x & 1023);
        bc[q1] = bf16_hi(v41.y) | (unsigned)(c41.y & 1023);
        bc[q2] = bf16_hi(v41.z) | (unsigned)(c41.z & 1023);
        bc[q3] = bf16_hi(v41.w) | (unsigned)(c41.w & 1023);
    }
    if (t == 0) {
        for (int i = hi - rem; i < hi; i++) {
            int r = erow[i], c = ecol[i];
            float v = evals[i];
            int pos = atomicAdd(&fr[r >> 10], 1);
            br[pos] = ((ull)__float_as_uint(v) << 32) | ((ull)(r & 1023) << LRSHIFT) | (unsigned)c;
            int pos2 = atomicAdd(&fc[c >> 10], 1);
            bc[pos2] = bf16_hi(v) | (unsigned)(c & 1023);
        }
    }
}

// ---- count: block (bucket b, chunk ch) reads its 1/8 edge slice ONCE, 4-edge ILP ----
__global__ __launch_bounds__(TPB_CP)
void count_kernel(const ull* __restrict__ br, const unsigned int* __restrict__ bc,
                  const int* __restrict__ gfill_r, const int* __restrict__ gfill_c,
                  int* __restrict__ subcnt, float* __restrict__ subds,
                  float* __restrict__ subdsc, int cap) {
    __shared__ int cnt[BUCKET];
    __shared__ float ds[BUCKET];
    __shared__ float dsc[BUCKET];
    int b = blockIdx.x >> 3, ch = blockIdx.x & 7;
    int t = threadIdx.x;
    for (int k = t; k < BUCKET; k += TPB_CP) { cnt[k] = 0; ds[k] = 0.0f; dsc[k] = 0.0f; }
    __syncthreads();
    int s = b * cap;                              // cap mult of 64
    int e = gfill_r[b * 16];
    int len = ((((e - s) + 7) >> 3) + 3) & ~3;    // slice length mult of 4
    int cs = s + ch * len, ce = min(e, cs + len);
    int m = cs + ((ce - cs) & ~3);
    for (int i = cs + 4 * t; i < m; i += 4 * TPB_CP) {
        ull p0 = br[i];
        ull p1 = br[i + 1];
        ull p2 = br[i + 2];
        ull p3 = br[i + 3];
        int lr0 = (int)((p0 >> LRSHIFT) & LRMASK);
        int lr1 = (int)((p1 >> LRSHIFT) & LRMASK);
        int lr2 = (int)((p2 >> LRSHIFT) & LRMASK);
        int lr3 = (int)((p3 >> LRSHIFT) & LRMASK);
        atomicAdd(&cnt[lr0], 1);
        atomicAdd(&cnt[lr1], 1);
        atomicAdd(&cnt[lr2], 1);
        atomicAdd(&cnt[lr3], 1);
        atomicAdd(&ds[lr0], __uint_as_float((unsigned)(p0 >> 32)));
        atomicAdd(&ds[lr1], __uint_as_float((unsigned)(p1 >> 32)));
        atomicAdd(&ds[lr2], __uint_as_float((unsigned)(p2 >> 32)));
        atomicAdd(&ds[lr3], __uint_as_float((unsigned)(p3 >> 32)));
    }
    if (t == 0) {
        for (int i = m; i < ce; i++) {
            ull p = br[i];
            int lr = (int)((p >> LRSHIFT) & LRMASK);
            atomicAdd(&cnt[lr], 1);
            atomicAdd(&ds[lr], __uint_as_float((unsigned)(p >> 32)));
        }
    }
    int e2 = gfill_c[b * 16];
    int len2 = ((((e2 - s) + 7) >> 3) + 3) & ~3;
    int cs2 = s + ch * len2, ce2 = min(e2, cs2 + len2);
    int m2 = cs2 + ((ce2 - cs2) & ~3);
    for (int i = cs2 + 4 * t; i < m2; i += 4 * TPB_CP) {
        uint4 p = *(const uint4*)(bc + i);
        atomicAdd(&dsc[p.x & 0x3FFu], __uint_as_float(p.x & 0xffff0000u));
        atomicAdd(&dsc[p.y & 0x3FFu], __uint_as_float(p.y & 0xffff0000u));
        atomicAdd(&dsc[p.z & 0x3FFu], __uint_as_float(p.z & 0xffff0000u));
        atomicAdd(&dsc[p.w & 0x3FFu], __uint_as_float(p.w & 0xffff0000u));
    }
    if (t == 0) {
        for (int i = m2; i < ce2; i++) {
            unsigned int p = bc[i];
            atomicAdd(&dsc[p & 0x3FFu], __uint_as_float(p & 0xffff0000u));
        }
    }
    __syncthreads();
    size_t base = ((size_t)b * 8 + ch) * BUCKET;
    for (int k = t; k < BUCKET; k += TPB_CP) {
        subcnt[base + k] = cnt[k];
        subds[base + k]  = ds[k];
        subdsc[base + k] = dsc[k];
    }
}

// ---- combine: even-rounded scan -> rse (int2), per-chunk bases, inv_r, inv_c ----
__global__ __launch_bounds__(1024)
void combine_kernel(int* __restrict__ subcnt, const float* __restrict__ subds,
                    const float* __restrict__ subdsc,
                    int2* __restrict__ rse,
                    float* __restrict__ inv_r, float* __restrict__ inv_c,
                    int N, int cap) {
    __shared__ int tot[BUCKET];
    int b = blockIdx.x, t = threadIdx.x;
    size_t base = (size_t)b * 8 * BUCKET;
    int c8[8];
    int sum = 0;
    #pragma unroll
    for (int c = 0; c < 8; c++) { c8[c] = subcnt[base + c * BUCKET + t]; sum += c8[c]; }
    int sum2 = (sum + 1) & ~1;           // even-rounded slot count -> even row starts
    tot[t] = sum2;
    __syncthreads();
    for (int off = 1; off < BUCKET; off <<= 1) {
        int v = (t >= off) ? tot[t - off] : 0;
        __syncthreads();
        tot[t] += v;
        __syncthreads();
    }
    int excl = tot[t] - sum2;
    int node = b * BUCKET + t;
    int s = b * cap;
    if (node < N) {
        int2 se;
        se.x = s + excl;
        se.y = s + excl + sum;
        rse[node] = se;
    }
    int run = s + excl;
    #pragma unroll
    for (int c = 0; c < 8; c++) { int v = c8[c]; subcnt[base + c * BUCKET + t] = run; run += v; }
    float d = 0.0f, dc = 0.0f;
    #pragma unroll
    for (int c = 0; c < 8; c++) { d += subds[base + c * BUCKET + t]; dc += subdsc[base + c * BUCKET + t]; }
    inv_r[b * BUCKET + t] = 1.0f / (sqrtf(d) + 1e-8f);
    inv_c[b * BUCKET + t] = 1.0f / (sqrtf(dc) + 1e-8f);
}

// ---- place: ranked placement, 4-edge ILP; 4 B entry = col<<15 | f16w>>1 ----
__global__ __launch_bounds__(TPB_CP)
void place_kernel(const ull* __restrict__ br, const int* __restrict__ gfill_r,
                  const int* __restrict__ pbase, const float* __restrict__ inv_r,
                  const float* __restrict__ inv_c,
                  unsigned int* __restrict__ cw, int cap) {
    __shared__ int fill[BUCKET];
    __shared__ float irs[BUCKET];
    int b = blockIdx.x >> 3, ch = blockIdx.x & 7;
    int t = threadIdx.x;
    size_t pb = ((size_t)b * 8 + ch) * BUCKET;
    for (int k = t; k < BUCKET; k += TPB_CP) {
        fill[k] = pbase[pb + k];
        irs[k]  = inv_r[b * BUCKET + k];
    }
    __syncthreads();
    int s = b * cap;
    int e = gfill_r[b * 16];
    int len = ((((e - s) + 7) >> 3) + 3) & ~3;
    int cs = s + ch * len, ce = min(e, cs + len);
    int m = cs + ((ce - cs) & ~3);
    for (int i = cs + 4 * t; i < m; i += 4 * TPB_CP) {
        ull p0 = br[i];
        ull p1 = br[i + 1];
        ull p2 = br[i + 2];
        ull p3 = br[i + 3];
        int c0 = (int)(p0 & CMASK), c1 = (int)(p1 & CMASK);
        int c2 = (int)(p2 & CMASK), c3 = (int)(p3 & CMASK);
        int lr0 = (int)((p0 >> LRSHIFT) & LRMASK);
        int lr1 = (int)((p1 >> LRSHIFT) & LRMASK);
        int lr2 = (int)((p2 >> LRSHIFT) & LRMASK);
        int lr3 = (int)((p3 >> LRSHIFT) & LRMASK);
        float v0 = __uint_as_float((unsigned)(p0 >> 32));
        float v1 = __uint_as_float((unsigned)(p1 >> 32));
        float v2 = __uint_as_float((unsigned)(p2 >> 32));
        float v3 = __uint_as_float((unsigned)(p3 >> 32));
        int pos0 = atomicAdd(&fill[lr0], 1);
        int pos1 = atomicAdd(&fill[lr1], 1);
        int pos2 = atomicAdd(&fill[lr2], 1);
        int pos3 = atomicAdd(&fill[lr3], 1);
        float w0 = v0 * inv_c[c0] * irs[lr0];
        float w1 = v1 * inv_c[c1] * irs[lr1];
        float w2 = v2 * inv_c[c2] * irs[lr2];
        float w3 = v3 * inv_c[c3] * irs[lr3];
        cw[pos0] = ((unsigned)c0 << 15) | ((pk_f16x2(w0, w0) & 0xFFFFu) >> 1);
        cw[pos1] = ((unsigned)c1 << 15) | ((pk_f16x2(w1, w1) & 0xFFFFu) >> 1);
        cw[pos2] = ((unsigned)c2 << 15) | ((pk_f16x2(w2, w2) & 0xFFFFu) >> 1);
        cw[pos3] = ((unsigned)c3 << 15) | ((pk_f16x2(w3, w3) & 0xFFFFu) >> 1);
    }
    if (t == 0) {
        for (int i = m; i < ce; i++) {
            ull p = br[i];
            int c = (int)(p & CMASK);
            int lr = (int)((p >> LRSHIFT) & LRMASK);
            float v = __uint_as_float((unsigned)(p >> 32));
            int pos = atomicAdd(&fill[lr], 1);
            float wv = v * inv_c[c] * irs[lr];
            cw[pos] = ((unsigned)c << 15) | ((pk_f16x2(wv, wv) & 0xFFFFu) >> 1);
        }
    }
}

// ---- cvt: fb0 = f16(nf); 4 floats/thread (acc init folded into spmm layer 1) ----
__global__ void cvt_kernel(const float* __restrict__ src,
                           unsigned int* __restrict__ dst, long n4) {
    long i = (long)blockIdx.x * blockDim.x + threadIdx.x;
    if (i < n4) {
        float4 v = ((const float4*)src)[i];
        uint2 o;
        o.x = pk_f16x2(v.x, v.y);
        o.y = pk_f16x2(v.z, v.w);
        ((uint2*)dst)[i] = o;
    }
}

// ---- SpMM: wave per row, uint2 cw pairs, v_pk_fma_f16, packed-f16 epilogue ----
__global__ __launch_bounds__(256)
void spmm_f16_kernel(const int2* __restrict__ rse,
                     const unsigned int* __restrict__ cw,
                     const unsigned short* __restrict__ fin,
                     unsigned short* __restrict__ fout,
                     unsigned short* __restrict__ acc16, int N,
                     int writeOut, int initAcc) {
    int wid = blockIdx.x * (blockDim.x >> 6) + (threadIdx.x >> 6);   // row
    if (wid >= N) return;
    int lane = threadIdx.x & 63;
    int g = lane >> 3;          // edge-pair slot 0..7 (16 edges per iteration)
    int h = lane & 7;           // feature chunk (8 f16 = 16 B)
    int2 se = rse[wid];
    int s = se.x, e = se.y;     // s even -> uint2-aligned cw pairs
    half2_t a2[8];
    #pragma unroll
    for (int k = 0; k < 8; k++) a2[k] = (half2_t)0;

    int nfull = (e - s) >> 4;
    int base = s;
    for (int it = 0; it < nfull; it++, base += 16) {
        int j0 = base + 2 * g;
        uint2 pw = *(const uint2*)(cw + j0);
        int c0 = (int)(pw.x >> 15);
        int c1 = (int)(pw.y >> 15);
        uint4 q0 = ((const uint4*)(fin + ((long)c0 << 6)))[h];
        uint4 q1 = ((const uint4*)(fin + ((long)c1 << 6)))[h];
        half2_t w0 = dup_lo16(pw.x << 1);
        half2_t w1 = dup_lo16(pw.y << 1);
        a2[0] += w0 * __builtin_bit_cast(half2_t, q0.x);
        a2[1] += w0 * __builtin_bit_cast(half2_t, q0.y);
        a2[2] += w0 * __builtin_bit_cast(half2_t, q0.z);
        a2[3] += w0 * __builtin_bit_cast(half2_t, q0.w);
        a2[4] += w1 * __builtin_bit_cast(half2_t, q1.x);
        a2[5] += w1 * __builtin_bit_cast(half2_t, q1.y);
        a2[6] += w1 * __builtin_bit_cast(half2_t, q1.z);
        a2[7] += w1 * __builtin_bit_cast(half2_t, q1.w);
    }
    if (base < e) {
        int j0 = base + 2 * g, j1 = j0 + 1;
        uint2 pw = *(const uint2*)(cw + j0);   // in padded region; poison col < 2^17
        int c0 = (int)(pw.x >> 15);
        int c1 = (int)(pw.y >> 15);
        half2_t w0 = (j0 < e) ? dup_lo16(pw.x << 1) : (half2_t)0;
        half2_t w1 = (j1 < e) ? dup_lo16(pw.y << 1) : (half2_t)0;
        uint4 q0 = ((const uint4*)(fin + ((long)c0 << 6)))[h];
        uint4 q1 = ((const uint4*)(fin + ((long)c1 << 6)))[h];
        a2[0] += w0 * __builtin_bit_cast(half2_t, q0.x);
        a2[1] += w0 * __builtin_bit_cast(half2_t, q0.y);
        a2[2] += w0 * __builtin_bit_cast(half2_t, q0.z);
        a2[3] += w0 * __builtin_bit_cast(half2_t, q0.w);
        a2[4] += w1 * __builtin_bit_cast(half2_t, q1.x);
        a2[5] += w1 * __builtin_bit_cast(half2_t, q1.y);
        a2[6] += w1 * __builtin_bit_cast(half2_t, q1.z);
        a2[7] += w1 * __builtin_bit_cast(half2_t, q1.w);
    }

    // packed-f16 epilogue
    #pragma unroll
    for (int k = 0; k < 4; k++) a2[k] += a2[k + 4];
    #pragma unroll
    for (int k = 0; k < 4; k++) {
        a2[k] += h2_shfl_xor(a2[k], 8);
        a2[k] += h2_shfl_xor(a2[k], 16);
        a2[k] += h2_shfl_xor(a2[k], 32);
    }
    half2_t ssh = a2[0] * a2[0];
    ssh += a2[1] * a2[1];
    ssh += a2[2] * a2[2];
    ssh += a2[3] * a2[3];
    float ss = (float)ssh[0] + (float)ssh[1];
    ss += __shfl_xor(ss, 1);
    ss += __shfl_xor(ss, 2);
    ss += __shfl_xor(ss, 4);
    float s2 = fminf(1.0f / fmaxf(sqrtf(ss), 1e-12f), 6.0e4f);  // clamp: f16-safe
    if (g == 0) {
        if (writeOut) {
            uint4 o;
            o.x = __builtin_bit_cast(unsigned int, a2[0]);
            o.y = __builtin_bit_cast(unsigned int, a2[1]);
            o.z = __builtin_bit_cast(unsigned int, a2[2]);
            o.w = __builtin_bit_cast(unsigned int, a2[3]);
            ((uint4*)(fout + ((long)wid << 6)))[h] = o;
        }
        half2_t s2h = __builtin_bit_cast(half2_t, pk_f16x2(s2, s2));
        uint4* ap = (uint4*)(acc16 + ((long)wid << 6)) + h;
        // layer 1: acc starts at f16(nf) = fin[wid] (avoids cvt writing acc16)
        uint4 old = initAcc ? ((const uint4*)(fin + ((long)wid << 6)))[h] : *ap;
        uint4 nw;
        nw.x = __builtin_bit_cast(unsigned int, __builtin_bit_cast(half2_t, old.x) + a2[0] * s2h);
        nw.y = __builtin_bit_cast(unsigned int, __builtin_bit_cast(half2_t, old.y) + a2[1] * s2h);
        nw.z = __builtin_bit_cast(unsigned int, __builtin_bit_cast(half2_t, old.z) + a2[2] * s2h);
        nw.w = __builtin_bit_cast(unsigned int, __builtin_bit_cast(half2_t, old.w) + a2[3] * s2h);
        *ap = nw;
    }
}

// ---- BPR loss (acc in f16) ----
__global__ void loss_terms_kernel(const unsigned short* __restrict__ acc16,
                                  const int* __restrict__ a_id, const int* __restrict__ p_id,
                                  const int* __restrict__ n_id,
                                  float* __restrict__ terms, int B) {
    long gid = (long)blockIdx.x * blockDim.x + threadIdx.x;
    int b = (int)(gid >> 6);
    int lane = threadIdx.x & 63;
    if (b < B) {
        int ia = a_id[b], ip = p_id[b], in2 = n_id[b];
        float a = (float)__builtin_bit_cast(_Float16, acc16[(long)ia * DDIM + lane]);
        float p = (float)__builtin_bit_cast(_Float16, acc16[(long)ip * DDIM + lane]);
        float n = (float)__builtin_bit_cast(_Float16, acc16[(long)in2 * DDIM + lane]);
        float dp = a * p, dn = a * n;
        #pragma unroll
        for (int off = 1; off < 64; off <<= 1) { dp += __shfl_xor(dp, off); dn += __shfl_xor(dn, off); }
        if (lane == 0) {
            float x = (dp - dn) * 0.0625f;   // node_rep = acc/4 -> preds scale 1/16
            terms[b] = fmaxf(-x, 0.0f) + log1pf(expf(-fabsf(x)));
        }
    }
}

__global__ void reduce_kernel(const float* __restrict__ terms, float* __restrict__ out, int B) {
    __shared__ float sm[256];
    float s = 0.0f;
    for (int i = threadIdx.x; i < B; i += 256) s += terms[i];
    sm[threadIdx.x] = s;
    __syncthreads();
    for (int stride = 128; stride > 0; stride >>= 1) {
        if (threadIdx.x < stride) sm[threadIdx.x] += sm[threadIdx.x + stride];
        __syncthreads();
    }
    if (threadIdx.x == 0) out[0] = sm[0] / (float)B;
}

extern "C" void kernel_launch(void* const* d_in, const int* in_sizes, int n_in,
                              void* d_out, int out_size, void* d_ws, size_t ws_size,
                              hipStream_t stream) {
    const float* nf    = (const float*)d_in[0];
    const int*   erow  = (const int*)d_in[1];
    const int*   ecol  = (const int*)d_in[2];
    const float* evals = (const float*)d_in[3];
    const int*   a_id  = (const int*)d_in[4];
    const int*   p_id  = (const int*)d_in[5];
    const int*   n_id  = (const int*)d_in[6];

    int N = in_sizes[0] / DDIM;
    int E = in_sizes[1];
    int B = in_sizes[4];
    int NB = (N + BUCKET - 1) / BUCKET;
    int chunk = (((E + NBLK - 1) / NBLK) + 3) & ~3;   // multiple of 4 -> aligned quad loads
    int Npad = NB * BUCKET;

    // bucket capacity: mean + ~8.3% + 2048 (even-rounding pad + >10 sigma)
    long capl = ((long)E * BUCKET) / N;
    int cap = (int)(capl + capl / 12 + 2048);
    cap = (cap + 63) & ~63;

    size_t regionA = (size_t)cap * NB * 8;            // br (8 B), later fb0+fb1
    size_t regionB = (size_t)cap * NB * 4;            // bc (4 B), later cw (4 B)
    size_t featB16 = (size_t)N * DDIM * 2;
    if (regionA < 2 * featB16) regionA = 2 * featB16;
    size_t subBytes = (size_t)NB * 8 * BUCKET * 4;

    char* w = (char*)d_ws;
    ull*  br     = (ull*)w;
    char* regAp  = w;                 w += regionA;
    unsigned int* bc = (unsigned int*)w;
    unsigned int* cw = (unsigned int*)w;  w += regionB + 64;   // +64: spmm tail overread pad
    unsigned int* acc16 = (unsigned int*)w;  w += featB16;
    int* subcnt  = (int*)w;           w += subBytes;    // becomes pbase in combine
    float* subds = (float*)w;         w += subBytes;
    float* subdsc= (float*)w;         w += subBytes;
    float* inv_c = (float*)w;         w += (size_t)Npad * 4;
    float* inv_r = (float*)w;         w += (size_t)Npad * 4;
    int2* rse    = (int2*)w;          w += (size_t)N * 8;
    int* gfill_r = (int*)w;           w += (size_t)NB * 16 * 4;
    int* gfill_c = (int*)w;           w += (size_t)NB * 16 * 4;
    float* terms = (float*)w;         w += (size_t)B * 4;

    unsigned short* fb0 = (unsigned short*)regAp;             // aliases br (dead after place)
    unsigned short* fb1 = (unsigned short*)(regAp + featB16);

    init_fill_kernel<<<1, 128, 0, stream>>>(gfill_r, gfill_c, NB, cap);
    binning_kernel<<<NBLK, TPB_BIN, 0, stream>>>(erow, ecol, evals, gfill_r, gfill_c,
                                                 br, bc, E, NB, chunk);
    count_kernel<<<NB * 8, TPB_CP, 0, stream>>>(br, bc, gfill_r, gfill_c,
                                                subcnt, subds, subdsc, cap);
    combine_kernel<<<NB, 1024, 0, stream>>>(subcnt, subds, subdsc, rse,
                                            inv_r, inv_c, N, cap);
    place_kernel<<<NB * 8, TPB_CP, 0, stream>>>(br, gfill_r, subcnt, inv_r, inv_c, cw, cap);

    long n4 = (long)N * DDIM / 4;
    cvt_kernel<<<(unsigned)((n4 + 255) / 256), 256, 0, stream>>>(nf, (unsigned int*)fb0, n4);

    unsigned spmmGrid = (unsigned)((N + 3) / 4);   // 4 waves (rows) per 256-thread block
    spmm_f16_kernel<<<spmmGrid, 256, 0, stream>>>(rse, cw, fb0, fb1,
                                                  (unsigned short*)acc16, N, 1, 1);
    spmm_f16_kernel<<<spmmGrid, 256, 0, stream>>>(rse, cw, fb1, fb0,
                                                  (unsigned short*)acc16, N, 1, 0);
    spmm_f16_kernel<<<spmmGrid, 256, 0, stream>>>(rse, cw, fb0, fb1,
                                                  (unsigned short*)acc16, N, 0, 0);

    loss_terms_kernel<<<(unsigned)(((long)B * 64 + 255) / 256), 256, 0, stream>>>(
        (const unsigned short*)acc16, a_id, p_id, n_id, terms, B);
    reduce_kernel<<<1, 256, 0, stream>>>(terms, (float*)d_out, B);
}